// Round 4
// baseline (2091.365 us; speedup 1.0000x reference)
//
#include <hip/hip_runtime.h>

static constexpr int NBRS = 21;
static constexpr int Nv   = 12288;
static constexpr int BV   = 4 * Nv;            // 49152 rows
static constexpr float BN_EPS = 1e-5f;

// ---------------- SPMM (C=8, scalar)
template<bool CHEB2>
__global__ void spmm8_kernel(float* __restrict__ y, const float* __restrict__ x,
                             const float* __restrict__ x0,
                             const float* __restrict__ val, const int* __restrict__ col)
{
    int idx = blockIdx.x * 256 + threadIdx.x;
    int c = idx % 8;
    int v = (idx / 8) % Nv;
    int b = idx / (8 * Nv);
    int e0 = v * NBRS;
    float acc = 0.f;
    #pragma unroll
    for (int j = 0; j < NBRS; ++j) {
        int u = col[e0 + j];
        acc = fmaf(val[e0 + j], x[((size_t)b * Nv + u) * 8 + c], acc);
    }
    if (CHEB2) y[idx] = 2.f * acc - x0[idx];
    else       y[idx] = acc;
}

// ---------------- SPMM C=64, float4, optional fused BN+relu on gather and/or x0
template<bool CHEB2, bool BNG, bool BNX0>
__global__ __launch_bounds__(256)
void spmm64_kernel(float* __restrict__ y, const float* __restrict__ x,
                   const float* __restrict__ x0,
                   const float* __restrict__ val, const int* __restrict__ col,
                   const float* __restrict__ bn_a, const float* __restrict__ bn_b)
{
    int idx = blockIdx.x * 256 + threadIdx.x;   // over BV*16
    int q = idx % 16;
    int v = (idx / 16) % Nv;
    int b = idx / (16 * Nv);
    int e0 = v * NBRS;
    const float4* x4 = (const float4*)x;
    float4 a4, b4;
    if (BNG || (CHEB2 && BNX0)) {
        a4 = ((const float4*)bn_a)[q];
        b4 = ((const float4*)bn_b)[q];
    }
    float4 acc = {0.f, 0.f, 0.f, 0.f};
    #pragma unroll
    for (int j = 0; j < NBRS; ++j) {
        int u = col[e0 + j];
        float a = val[e0 + j];
        float4 xv = x4[(size_t)(b * Nv + u) * 16 + q];
        if (BNG) {
            xv.x = fmaxf(fmaf(xv.x, a4.x, b4.x), 0.f);
            xv.y = fmaxf(fmaf(xv.y, a4.y, b4.y), 0.f);
            xv.z = fmaxf(fmaf(xv.z, a4.z, b4.z), 0.f);
            xv.w = fmaxf(fmaf(xv.w, a4.w, b4.w), 0.f);
        }
        acc.x = fmaf(a, xv.x, acc.x);
        acc.y = fmaf(a, xv.y, acc.y);
        acc.z = fmaf(a, xv.z, acc.z);
        acc.w = fmaf(a, xv.w, acc.w);
    }
    if (CHEB2) {
        float4 pv = ((const float4*)x0)[idx];
        if (BNX0) {
            pv.x = fmaxf(fmaf(pv.x, a4.x, b4.x), 0.f);
            pv.y = fmaxf(fmaf(pv.y, a4.y, b4.y), 0.f);
            pv.z = fmaxf(fmaf(pv.z, a4.z, b4.z), 0.f);
            pv.w = fmaxf(fmaf(pv.w, a4.w, b4.w), 0.f);
        }
        acc.x = 2.f * acc.x - pv.x;
        acc.y = 2.f * acc.y - pv.y;
        acc.z = 2.f * acc.z - pv.z;
        acc.w = 2.f * acc.w - pv.w;
    }
    ((float4*)y)[idx] = acc;
}

// ---------------- LDS-staged GEMM with float4 LDS reads.
// out[m,o] = sum_ki x[m,ki] * w[ki,o] (+bias); optional fused BN+relu on x0 at
// staging, fused BN-stats in epilogue (reduce LDS unions with the x tile).
template<int FOUT, int KFIN, int FIN, int TO, int OTHR, int RGRP, int RPG, int NSRC,
         bool STATS, bool BN0, bool HAS_BIAS, bool PACKOUT>
__global__ __launch_bounds__(OTHR * RGRP)
void gemm_lds_kernel(const float* __restrict__ x0, const float* __restrict__ x1,
                     const float* __restrict__ x2,
                     const float* __restrict__ w, const float* __restrict__ bias,
                     const float* __restrict__ bn_a, const float* __restrict__ bn_b,
                     float* __restrict__ out, float2* __restrict__ partial)
{
    constexpr int THREADS = OTHR * RGRP;
    constexpr int ROWS = RGRP * RPG;
    constexpr int LDK = KFIN + 4;                       // pad: bank-spread + f4 align
    constexpr size_t XS_B  = (size_t)ROWS * LDK * 4;
    constexpr size_t RED_B = STATS ? (size_t)RGRP * (FOUT + 1) * 8 : 0;
    constexpr size_t SMEM  = XS_B > RED_B ? XS_B : RED_B;
    __shared__ __align__(16) char smem[SMEM];
    float* xs = (float*)smem;

    const int tid = threadIdx.x;
    const int m0 = blockIdx.x * ROWS;

    // ---- stage x tile (coalesced float4), optional BN+relu on the x0 portion
    constexpr int NF4 = ROWS * KFIN / 4;
    for (int f = tid; f < NF4; f += THREADS) {
        const int r  = f / (KFIN / 4);
        const int ki = (f % (KFIN / 4)) * 4;
        const float* src; int i; int kk;
        if constexpr (NSRC == 1) { src = x0; i = ki; kk = 0; }
        else { kk = ki / FIN; i = ki % FIN; src = (kk == 0) ? x0 : (kk == 1 ? x1 : x2); }
        float4 v = *(const float4*)(src + (size_t)(m0 + r) * FIN + i);
        if constexpr (BN0) {
            if (NSRC == 1 || kk == 0) {
                const float4 a4 = *(const float4*)(bn_a + i);
                const float4 b4 = *(const float4*)(bn_b + i);
                v.x = fmaxf(fmaf(v.x, a4.x, b4.x), 0.f);
                v.y = fmaxf(fmaf(v.y, a4.y, b4.y), 0.f);
                v.z = fmaxf(fmaf(v.z, a4.z, b4.z), 0.f);
                v.w = fmaxf(fmaf(v.w, a4.w, b4.w), 0.f);
            }
        }
        *(float4*)(xs + (size_t)r * LDK + ki) = v;
    }
    __syncthreads();

    const int othr = tid % OTHR;
    const int grp  = tid / OTHR;
    const int o0 = othr * TO;
    const int r0 = grp * RPG;

    float acc[RPG][TO];
    #pragma unroll
    for (int r = 0; r < RPG; ++r)
        #pragma unroll
        for (int t = 0; t < TO; ++t) acc[r][t] = 0.f;

    #pragma unroll 2
    for (int k4 = 0; k4 < KFIN / 4; ++k4) {
        const int ki = k4 * 4;
        float4 xv[RPG];
        #pragma unroll
        for (int r = 0; r < RPG; ++r)
            xv[r] = *(const float4*)(xs + (size_t)(r0 + r) * LDK + ki);
        #pragma unroll
        for (int j = 0; j < 4; ++j) {
            float wv[TO];
            {
                const float4 wa = *(const float4*)(w + (size_t)(ki + j) * FOUT + o0);
                wv[0] = wa.x; wv[1] = wa.y; wv[2] = wa.z; wv[3] = wa.w;
                if constexpr (TO == 8) {
                    const float4 wb = *(const float4*)(w + (size_t)(ki + j) * FOUT + o0 + 4);
                    wv[4] = wb.x; wv[5] = wb.y; wv[6] = wb.z; wv[7] = wb.w;
                }
            }
            #pragma unroll
            for (int r = 0; r < RPG; ++r) {
                const float xx = (j == 0) ? xv[r].x : (j == 1) ? xv[r].y
                               : (j == 2) ? xv[r].z : xv[r].w;
                #pragma unroll
                for (int t = 0; t < TO; ++t) acc[r][t] = fmaf(xx, wv[t], acc[r][t]);
            }
        }
    }
    __syncthreads();   // xs dead; smem reusable for stats reduce

    float bv[TO];
    if constexpr (HAS_BIAS) {
        const float4 ba = *(const float4*)(bias + o0);
        bv[0] = ba.x; bv[1] = ba.y; bv[2] = ba.z; bv[3] = ba.w;
        if constexpr (TO == 8) {
            const float4 bb = *(const float4*)(bias + o0 + 4);
            bv[4] = bb.x; bv[5] = bb.y; bv[6] = bb.z; bv[7] = bb.w;
        }
    } else {
        #pragma unroll
        for (int t = 0; t < TO; ++t) bv[t] = 0.f;
    }

    float s[TO], q[TO];
    #pragma unroll
    for (int t = 0; t < TO; ++t) { s[t] = 0.f; q[t] = 0.f; }

    #pragma unroll
    for (int r = 0; r < RPG; ++r) {
        float v[TO];
        #pragma unroll
        for (int t = 0; t < TO; ++t) {
            v[t] = acc[r][t] + bv[t];
            if constexpr (STATS) { s[t] += v[t]; q[t] = fmaf(v[t], v[t], q[t]); }
        }
        const int m = m0 + r0 + r;
        if constexpr (PACKOUT) {
            // TO==4: othr>>1 selects z_j (0..2, 3 dummy), othr&1 selects col half
            const int zj = othr >> 1, half = othr & 1;
            if (zj < 3)
                *(float4*)(out + ((size_t)zj * BV + m) * 8 + half * 4) =
                    make_float4(v[0], v[1], v[2], v[3]);
        } else {
            float* dst = out + (size_t)m * FOUT + o0;
            *(float4*)dst = make_float4(v[0], v[1], v[2], v[3]);
            if constexpr (TO == 8)
                *(float4*)(dst + 4) = make_float4(v[4], v[5], v[6], v[7]);
        }
    }

    if constexpr (STATS) {
        float2* red = (float2*)smem;              // [RGRP][FOUT+1]
        #pragma unroll
        for (int t = 0; t < TO; ++t)
            red[(size_t)grp * (FOUT + 1) + o0 + t] = make_float2(s[t], q[t]);
        __syncthreads();
        for (int c = tid; c < FOUT; c += THREADS) {
            float rs = 0.f, rq = 0.f;
            #pragma unroll 4
            for (int g = 0; g < RGRP; ++g) {
                const float2 p = red[(size_t)g * (FOUT + 1) + c];
                rs += p.x; rq += p.y;
            }
            partial[(size_t)blockIdx.x * FOUT + c] = make_float2(rs, rq);
        }
    }
}

// ---------------- BN finalize: reduce per-block partials -> per-channel (a, b)
template<int C>
__global__ __launch_bounds__(1024)
void bn_finalize_kernel(const float2* __restrict__ partial,
                        const float* __restrict__ g, const float* __restrict__ b,
                        float* __restrict__ a_out, float* __restrict__ b_out,
                        float invN, int nblk)
{
    constexpr int G = 1024 / C;
    int c  = threadIdx.x / G;
    int gg = threadIdx.x % G;
    float s = 0.f, ss = 0.f;
    for (int k = gg; k < nblk; k += G) {
        float2 p = partial[(size_t)k * C + c];
        s += p.x; ss += p.y;
    }
    #pragma unroll
    for (int off = G / 2; off > 0; off >>= 1) {
        s  += __shfl_down(s, off);
        ss += __shfl_down(ss, off);
    }
    if (gg == 0) {
        float m = s * invN;
        float var = ss * invN - m * m;
        float a = g[c] * rsqrtf(var + BN_EPS);
        a_out[c] = a;
        b_out[c] = b[c] - m * a;
    }
}

// ---------------- BN apply (float4), for C=256 tensors only
template<int C, bool RELU, bool ADD>
__global__ __launch_bounds__(256)
void bn_apply_kernel(float* __restrict__ out, const float* __restrict__ x,
                     const float* __restrict__ base,
                     const float* __restrict__ bn_a, const float* __restrict__ bn_b)
{
    int i = blockIdx.x * 256 + threadIdx.x;   // float4 index
    float4 v = ((const float4*)x)[i];
    int c0 = (i * 4) % C;
    float4 a4 = *reinterpret_cast<const float4*>(bn_a + c0);
    float4 b4 = *reinterpret_cast<const float4*>(bn_b + c0);
    float4 r;
    r.x = fmaf(v.x, a4.x, b4.x);
    r.y = fmaf(v.y, a4.y, b4.y);
    r.z = fmaf(v.z, a4.z, b4.z);
    r.w = fmaf(v.w, a4.w, b4.w);
    if (ADD) {
        float4 bvv = ((const float4*)base)[i];
        r.x += bvv.x; r.y += bvv.y; r.z += bvv.z; r.w += bvv.w;
    }
    if (RELU) {
        r.x = fmaxf(r.x, 0.f); r.y = fmaxf(r.y, 0.f);
        r.z = fmaxf(r.z, 0.f); r.w = fmaxf(r.w, 0.f);
    }
    ((float4*)out)[i] = r;
}

// ---------------- conv3 weight packer: [3][256][8] -> [256][32] (+ padded bias)
__global__ void pack_conv3_kernel(const float* __restrict__ w, const float* __restrict__ bias,
                                  float* __restrict__ wpack, float* __restrict__ bpack)
{
    int t = blockIdx.x * 256 + threadIdx.x;
    if (t < 256 * 32) {
        int ki = t / 32, c = t % 32;
        int j = c / 8, o = c % 8;
        wpack[t] = (j < 3) ? w[(size_t)j * 2048 + ki * 8 + o] : 0.f;
    }
    if (t < 32) bpack[t] = (t < 8) ? bias[t] : 0.f;
}

// ---------------- conv3 tail helpers
__global__ void combine_kernel(float* __restrict__ e, const float* __restrict__ z1,
                               const float* __restrict__ t)
{
    int i = blockIdx.x * 256 + threadIdx.x;
    e[i] = fmaf(2.f, t[i], z1[i]);
}

__global__ void final_add_kernel(float* __restrict__ out, const float* __restrict__ z0,
                                 const float* __restrict__ z2, const float* __restrict__ s)
{
    int i = blockIdx.x * 256 + threadIdx.x;
    out[i] = z0[i] - z2[i] + s[i];
}

extern "C" void kernel_launch(void* const* d_in, const int* in_sizes, int n_in,
                              void* d_out, int out_size, void* d_ws, size_t ws_size,
                              hipStream_t stream)
{
    const float* x       = (const float*)d_in[0];
    const int*   col     = (const int*)  d_in[2];
    const float* eval_   = (const float*)d_in[3];
    const float* conv1_w = (const float*)d_in[4];
    const float* conv1_b = (const float*)d_in[5];
    const float* bn1_g   = (const float*)d_in[6];
    const float* bn1_b   = (const float*)d_in[7];
    const float* conv2_w = (const float*)d_in[8];
    const float* conv2_b = (const float*)d_in[9];
    const float* bn2_g   = (const float*)d_in[10];
    const float* bn2_b   = (const float*)d_in[11];
    const float* bt_c1w  = (const float*)d_in[12];
    const float* bt_c1b  = (const float*)d_in[13];
    const float* bt_c2w  = (const float*)d_in[14];
    const float* bt_c2b  = (const float*)d_in[15];
    const float* bt_c3w  = (const float*)d_in[16];
    const float* bt_c3b  = (const float*)d_in[17];
    const float* btbn1g  = (const float*)d_in[18];
    const float* btbn1b  = (const float*)d_in[19];
    const float* btbn2g  = (const float*)d_in[20];
    const float* btbn2b  = (const float*)d_in[21];
    const float* btbn3g  = (const float*)d_in[22];
    const float* btbn3b  = (const float*)d_in[23];
    const float* conv3_w = (const float*)d_in[24];
    const float* conv3_b = (const float*)d_in[25];
    float* out = (float*)d_out;

    float* ws = (float*)d_ws;
    float* h2    = ws;                         // BV*256
    float* y3    = h2 + (size_t)BV * 256;      // BV*256 (aliased as stats partial)
    float* t64a  = y3 + (size_t)BV * 256;      // BV*64
    float* t64b  = t64a + (size_t)BV * 64;     // BV*64
    float* t64c  = t64b + (size_t)BV * 64;     // BV*64
    float* t64d  = t64c + (size_t)BV * 64;     // BV*64
    float* aarr  = t64d + (size_t)BV * 64;     // 11*256
    float* barr  = aarr + 11 * 256;            // 11*256
    float* wpack = barr + 11 * 256;            // 256*32
    float* bpack = wpack + 256 * 32;           // 32
    float2* partY = (float2*)y3;               // partial when y3 is dead
    float2* partC = (float2*)t64c;             // partial for cheb3 (y3 being written)

    const float invN = 1.f / (float)BV;
    const int NGB = BV / 32;                   // 1536 GEMM blocks

    // ---------- Stage A: conv1 (8 -> 64), K=3 ----------
    spmm8_kernel<false><<<BV * 8 / 256, 256, 0, stream>>>(t64a, x, nullptr, eval_, col);
    spmm8_kernel<true ><<<BV * 8 / 256, 256, 0, stream>>>(t64b, t64a, x, eval_, col);
    gemm_lds_kernel<64, 24, 8, 4, 16, 16, 2, 3, true, false, true, false>
        <<<NGB, 256, 0, stream>>>(x, t64a, t64b, conv1_w, conv1_b, nullptr, nullptr, t64c, partY);
    bn_finalize_kernel<64><<<1, 1024, 0, stream>>>(partY, bn1_g, bn1_b, aarr, barr, invN, NGB);

    // ---------- Stage B: conv2 (64 -> 256), K=3, x0-BN fused ----------
    spmm64_kernel<false, true, false><<<BV * 16 / 256, 256, 0, stream>>>(t64a, t64c, nullptr, eval_, col, aarr, barr);
    spmm64_kernel<true, false, true ><<<BV * 16 / 256, 256, 0, stream>>>(t64b, t64a, t64c, eval_, col, aarr, barr);
    gemm_lds_kernel<256, 192, 64, 8, 32, 8, 4, 3, true, true, true, false>
        <<<NGB, 256, 0, stream>>>(t64c, t64a, t64b, conv2_w, conv2_b, aarr, barr, h2, partY);
    bn_finalize_kernel<256><<<1, 1024, 0, stream>>>(partY, bn2_g, bn2_b, aarr + 256, barr + 256, invN, NGB);
    bn_apply_kernel<256, true, false><<<BV, 256, 0, stream>>>(h2, h2, nullptr, aarr + 256, barr + 256);

    // ---------- Stage C: 3 bottlenecks ----------
    for (int i = 0; i < 3; ++i) {
        float* aA = aarr + (2 + i * 3) * 256; float* bA = barr + (2 + i * 3) * 256;
        float* aB = aarr + (3 + i * 3) * 256; float* bB = barr + (3 + i * 3) * 256;
        float* aC = aarr + (4 + i * 3) * 256; float* bC = barr + (4 + i * 3) * 256;

        // cheb1: K=1, 256->64, stats fused
        gemm_lds_kernel<64, 256, 256, 4, 16, 16, 2, 1, true, false, true, false>
            <<<NGB, 256, 0, stream>>>(h2, nullptr, nullptr,
                                      bt_c1w + (size_t)i * 256 * 64, bt_c1b + i * 64,
                                      nullptr, nullptr, t64c, partY);
        bn_finalize_kernel<64><<<1, 1024, 0, stream>>>(partY, btbn1g + i * 64, btbn1b + i * 64, aA, bA, invN, NGB);

        // cheb2: K=3, 64->64; BN1 fused into gathers and x0-staging
        spmm64_kernel<false, true, false><<<BV * 16 / 256, 256, 0, stream>>>(t64a, t64c, nullptr, eval_, col, aA, bA);
        spmm64_kernel<true, false, true ><<<BV * 16 / 256, 256, 0, stream>>>(t64b, t64a, t64c, eval_, col, aA, bA);
        gemm_lds_kernel<64, 192, 64, 4, 16, 16, 2, 3, true, true, true, false>
            <<<NGB, 256, 0, stream>>>(t64c, t64a, t64b,
                                      bt_c2w + (size_t)i * 3 * 64 * 64, bt_c2b + i * 64,
                                      aA, bA, t64d, partY);
        bn_finalize_kernel<64><<<1, 1024, 0, stream>>>(partY, btbn2g + i * 64, btbn2b + i * 64, aB, bB, invN, NGB);

        // cheb3: K=1, 64->256; BN2 fused into x0-staging; stats partial -> t64c
        gemm_lds_kernel<256, 64, 64, 8, 32, 8, 4, 1, true, true, true, false>
            <<<NGB, 256, 0, stream>>>(t64d, nullptr, nullptr,
                                      bt_c3w + (size_t)i * 64 * 256, bt_c3b + i * 256,
                                      aB, bB, y3, partC);
        bn_finalize_kernel<256><<<1, 1024, 0, stream>>>(partC, btbn3g + i * 256, btbn3b + i * 256, aC, bC, invN, NGB);
        // BN3 apply + residual add into h2
        bn_apply_kernel<256, false, true><<<BV, 256, 0, stream>>>(h2, y3, h2, aC, bC);
    }

    // ---------- Stage D: conv3 (256 -> 8), K=3, commuted: out = z0 - z2 + L(z1 + 2*L*z2) ----------
    float* z0 = t64a;
    float* z1 = z0 + (size_t)BV * 8;
    float* z2 = z1 + (size_t)BV * 8;
    float* tt = z2 + (size_t)BV * 8;
    float* ee = tt + (size_t)BV * 8;
    float* sb = ee + (size_t)BV * 8;

    pack_conv3_kernel<<<32, 256, 0, stream>>>(conv3_w, conv3_b, wpack, bpack);
    gemm_lds_kernel<32, 256, 256, 4, 8, 32, 1, 1, false, false, true, true>
        <<<NGB, 256, 0, stream>>>(h2, nullptr, nullptr, wpack, bpack, nullptr, nullptr, z0, nullptr);

    spmm8_kernel<false><<<BV * 8 / 256, 256, 0, stream>>>(tt, z2, nullptr, eval_, col);
    combine_kernel<<<BV * 8 / 256, 256, 0, stream>>>(ee, z1, tt);
    spmm8_kernel<false><<<BV * 8 / 256, 256, 0, stream>>>(sb, ee, nullptr, eval_, col);
    final_add_kernel<<<BV * 8 / 256, 256, 0, stream>>>(out, z0, z2, sb);

    (void)in_sizes; (void)n_in; (void)out_size; (void)ws_size;
}

// Round 5
// 1154.420 us; speedup vs baseline: 1.8116x; 1.8116x over previous
//
#include <hip/hip_runtime.h>

static constexpr int NBRS = 21;
static constexpr int Nv   = 12288;
static constexpr int BV   = 4 * Nv;            // 49152 rows
static constexpr float BN_EPS = 1e-5f;

// ---------------- SPMM (C=8, scalar)
template<bool CHEB2>
__global__ void spmm8_kernel(float* __restrict__ y, const float* __restrict__ x,
                             const float* __restrict__ x0,
                             const float* __restrict__ val, const int* __restrict__ col)
{
    int idx = blockIdx.x * 256 + threadIdx.x;
    int c = idx % 8;
    int v = (idx / 8) % Nv;
    int b = idx / (8 * Nv);
    int e0 = v * NBRS;
    float acc = 0.f;
    #pragma unroll
    for (int j = 0; j < NBRS; ++j) {
        int u = col[e0 + j];
        acc = fmaf(val[e0 + j], x[((size_t)b * Nv + u) * 8 + c], acc);
    }
    if (CHEB2) y[idx] = 2.f * acc - x0[idx];
    else       y[idx] = acc;
}

// ---------------- SPMM C=64, float4, optional fused BN+relu on gather and/or x0
template<bool CHEB2, bool BNG, bool BNX0>
__global__ __launch_bounds__(256)
void spmm64_kernel(float* __restrict__ y, const float* __restrict__ x,
                   const float* __restrict__ x0,
                   const float* __restrict__ val, const int* __restrict__ col,
                   const float* __restrict__ bn_a, const float* __restrict__ bn_b)
{
    int idx = blockIdx.x * 256 + threadIdx.x;   // over BV*16
    int q = idx % 16;
    int v = (idx / 16) % Nv;
    int b = idx / (16 * Nv);
    int e0 = v * NBRS;
    const float4* x4 = (const float4*)x;
    float4 a4, b4;
    if (BNG || (CHEB2 && BNX0)) {
        a4 = ((const float4*)bn_a)[q];
        b4 = ((const float4*)bn_b)[q];
    }
    float4 acc = {0.f, 0.f, 0.f, 0.f};
    #pragma unroll
    for (int j = 0; j < NBRS; ++j) {
        int u = col[e0 + j];
        float a = val[e0 + j];
        float4 xv = x4[(size_t)(b * Nv + u) * 16 + q];
        if (BNG) {
            xv.x = fmaxf(fmaf(xv.x, a4.x, b4.x), 0.f);
            xv.y = fmaxf(fmaf(xv.y, a4.y, b4.y), 0.f);
            xv.z = fmaxf(fmaf(xv.z, a4.z, b4.z), 0.f);
            xv.w = fmaxf(fmaf(xv.w, a4.w, b4.w), 0.f);
        }
        acc.x = fmaf(a, xv.x, acc.x);
        acc.y = fmaf(a, xv.y, acc.y);
        acc.z = fmaf(a, xv.z, acc.z);
        acc.w = fmaf(a, xv.w, acc.w);
    }
    if (CHEB2) {
        float4 pv = ((const float4*)x0)[idx];
        if (BNX0) {
            pv.x = fmaxf(fmaf(pv.x, a4.x, b4.x), 0.f);
            pv.y = fmaxf(fmaf(pv.y, a4.y, b4.y), 0.f);
            pv.z = fmaxf(fmaf(pv.z, a4.z, b4.z), 0.f);
            pv.w = fmaxf(fmaf(pv.w, a4.w, b4.w), 0.f);
        }
        acc.x = 2.f * acc.x - pv.x;
        acc.y = 2.f * acc.y - pv.y;
        acc.z = 2.f * acc.z - pv.z;
        acc.w = 2.f * acc.w - pv.w;
    }
    ((float4*)y)[idx] = acc;
}

// ---------------- LDS-staged GEMM with float4 LDS reads.
// out[m,o] = sum_ki x[m,ki] * w[ki,o] (+bias); optional fused BN+relu on x0 at
// staging, fused BN-stats in epilogue. partial layout: [FOUT][gridDim.x].
template<int FOUT, int KFIN, int FIN, int TO, int OTHR, int RGRP, int RPG, int NSRC,
         bool STATS, bool BN0, bool HAS_BIAS, bool PACKOUT>
__global__ __launch_bounds__(OTHR * RGRP)
void gemm_lds_kernel(const float* __restrict__ x0, const float* __restrict__ x1,
                     const float* __restrict__ x2,
                     const float* __restrict__ w, const float* __restrict__ bias,
                     const float* __restrict__ bn_a, const float* __restrict__ bn_b,
                     float* __restrict__ out, float2* __restrict__ partial)
{
    constexpr int THREADS = OTHR * RGRP;
    constexpr int ROWS = RGRP * RPG;
    constexpr int LDK = KFIN + 4;                       // pad: bank-spread + f4 align
    constexpr size_t XS_B  = (size_t)ROWS * LDK * 4;
    constexpr size_t RED_B = STATS ? (size_t)RGRP * (FOUT + 1) * 8 : 0;
    constexpr size_t SMEM  = XS_B > RED_B ? XS_B : RED_B;
    __shared__ __align__(16) char smem[SMEM];
    float* xs = (float*)smem;

    const int tid = threadIdx.x;
    const int m0 = blockIdx.x * ROWS;

    // ---- stage x tile (coalesced float4), optional BN+relu on the x0 portion
    constexpr int NF4 = ROWS * KFIN / 4;
    for (int f = tid; f < NF4; f += THREADS) {
        const int r  = f / (KFIN / 4);
        const int ki = (f % (KFIN / 4)) * 4;
        const float* src; int i; int kk;
        if constexpr (NSRC == 1) { src = x0; i = ki; kk = 0; }
        else { kk = ki / FIN; i = ki % FIN; src = (kk == 0) ? x0 : (kk == 1 ? x1 : x2); }
        float4 v = *(const float4*)(src + (size_t)(m0 + r) * FIN + i);
        if constexpr (BN0) {
            if (NSRC == 1 || kk == 0) {
                const float4 a4 = *(const float4*)(bn_a + i);
                const float4 b4 = *(const float4*)(bn_b + i);
                v.x = fmaxf(fmaf(v.x, a4.x, b4.x), 0.f);
                v.y = fmaxf(fmaf(v.y, a4.y, b4.y), 0.f);
                v.z = fmaxf(fmaf(v.z, a4.z, b4.z), 0.f);
                v.w = fmaxf(fmaf(v.w, a4.w, b4.w), 0.f);
            }
        }
        *(float4*)(xs + (size_t)r * LDK + ki) = v;
    }
    __syncthreads();

    const int othr = tid % OTHR;
    const int grp  = tid / OTHR;
    const int o0 = othr * TO;
    const int r0 = grp * RPG;

    float acc[RPG][TO];
    #pragma unroll
    for (int r = 0; r < RPG; ++r)
        #pragma unroll
        for (int t = 0; t < TO; ++t) acc[r][t] = 0.f;

    #pragma unroll 2
    for (int k4 = 0; k4 < KFIN / 4; ++k4) {
        const int ki = k4 * 4;
        float4 xv[RPG];
        #pragma unroll
        for (int r = 0; r < RPG; ++r)
            xv[r] = *(const float4*)(xs + (size_t)(r0 + r) * LDK + ki);
        #pragma unroll
        for (int j = 0; j < 4; ++j) {
            float wv[TO];
            {
                const float4 wa = *(const float4*)(w + (size_t)(ki + j) * FOUT + o0);
                wv[0] = wa.x; wv[1] = wa.y; wv[2] = wa.z; wv[3] = wa.w;
                if constexpr (TO == 8) {
                    const float4 wb = *(const float4*)(w + (size_t)(ki + j) * FOUT + o0 + 4);
                    wv[4] = wb.x; wv[5] = wb.y; wv[6] = wb.z; wv[7] = wb.w;
                }
            }
            #pragma unroll
            for (int r = 0; r < RPG; ++r) {
                const float xx = (j == 0) ? xv[r].x : (j == 1) ? xv[r].y
                               : (j == 2) ? xv[r].z : xv[r].w;
                #pragma unroll
                for (int t = 0; t < TO; ++t) acc[r][t] = fmaf(xx, wv[t], acc[r][t]);
            }
        }
    }
    __syncthreads();   // xs dead; smem reusable for stats reduce

    float bv[TO];
    if constexpr (HAS_BIAS) {
        const float4 ba = *(const float4*)(bias + o0);
        bv[0] = ba.x; bv[1] = ba.y; bv[2] = ba.z; bv[3] = ba.w;
        if constexpr (TO == 8) {
            const float4 bb = *(const float4*)(bias + o0 + 4);
            bv[4] = bb.x; bv[5] = bb.y; bv[6] = bb.z; bv[7] = bb.w;
        }
    } else {
        #pragma unroll
        for (int t = 0; t < TO; ++t) bv[t] = 0.f;
    }

    float s[TO], q[TO];
    #pragma unroll
    for (int t = 0; t < TO; ++t) { s[t] = 0.f; q[t] = 0.f; }

    #pragma unroll
    for (int r = 0; r < RPG; ++r) {
        float v[TO];
        #pragma unroll
        for (int t = 0; t < TO; ++t) {
            v[t] = acc[r][t] + bv[t];
            if constexpr (STATS) { s[t] += v[t]; q[t] = fmaf(v[t], v[t], q[t]); }
        }
        const int m = m0 + r0 + r;
        if constexpr (PACKOUT) {
            // TO==4: othr>>1 selects z_j (0..2, 3 dummy), othr&1 selects col half
            const int zj = othr >> 1, half = othr & 1;
            if (zj < 3)
                *(float4*)(out + ((size_t)zj * BV + m) * 8 + half * 4) =
                    make_float4(v[0], v[1], v[2], v[3]);
        } else {
            float* dst = out + (size_t)m * FOUT + o0;
            *(float4*)dst = make_float4(v[0], v[1], v[2], v[3]);
            if constexpr (TO == 8)
                *(float4*)(dst + 4) = make_float4(v[4], v[5], v[6], v[7]);
        }
    }

    if constexpr (STATS) {
        float2* red = (float2*)smem;              // [RGRP][FOUT+1]
        #pragma unroll
        for (int t = 0; t < TO; ++t)
            red[(size_t)grp * (FOUT + 1) + o0 + t] = make_float2(s[t], q[t]);
        __syncthreads();
        for (int c = tid; c < FOUT; c += THREADS) {
            float rs = 0.f, rq = 0.f;
            #pragma unroll 4
            for (int g = 0; g < RGRP; ++g) {
                const float2 p = red[(size_t)g * (FOUT + 1) + c];
                rs += p.x; rq += p.y;
            }
            // transposed layout: [FOUT][gridDim.x] -> coalesced finalize reads
            partial[(size_t)c * gridDim.x + blockIdx.x] = make_float2(rs, rq);
        }
    }
}

// ---------------- BN finalize: one block per channel, coalesced over [C][nblk]
__global__ __launch_bounds__(256)
void bn_finalize_kernel(const float2* __restrict__ partial,
                        const float* __restrict__ g, const float* __restrict__ b,
                        float* __restrict__ a_out, float* __restrict__ b_out,
                        float invN, int nblk)
{
    __shared__ float2 red[4];
    const int c = blockIdx.x;
    const float2* p = partial + (size_t)c * nblk;
    float s = 0.f, ss = 0.f;
    for (int k = threadIdx.x; k < nblk; k += 256) {
        const float2 v = p[k];
        s += v.x; ss += v.y;
    }
    #pragma unroll
    for (int off = 32; off > 0; off >>= 1) {
        s  += __shfl_down(s, off);
        ss += __shfl_down(ss, off);
    }
    if ((threadIdx.x & 63) == 0) red[threadIdx.x >> 6] = make_float2(s, ss);
    __syncthreads();
    if (threadIdx.x == 0) {
        float ts = 0.f, tq = 0.f;
        #pragma unroll
        for (int i = 0; i < 4; ++i) { ts += red[i].x; tq += red[i].y; }
        const float m = ts * invN;
        const float var = tq * invN - m * m;
        const float a = g[c] * rsqrtf(var + BN_EPS);
        a_out[c] = a;
        b_out[c] = b[c] - m * a;
    }
}

// ---------------- BN apply (float4), for C=256 tensors only
template<int C, bool RELU, bool ADD>
__global__ __launch_bounds__(256)
void bn_apply_kernel(float* __restrict__ out, const float* __restrict__ x,
                     const float* __restrict__ base,
                     const float* __restrict__ bn_a, const float* __restrict__ bn_b)
{
    int i = blockIdx.x * 256 + threadIdx.x;   // float4 index
    float4 v = ((const float4*)x)[i];
    int c0 = (i * 4) % C;
    float4 a4 = *reinterpret_cast<const float4*>(bn_a + c0);
    float4 b4 = *reinterpret_cast<const float4*>(bn_b + c0);
    float4 r;
    r.x = fmaf(v.x, a4.x, b4.x);
    r.y = fmaf(v.y, a4.y, b4.y);
    r.z = fmaf(v.z, a4.z, b4.z);
    r.w = fmaf(v.w, a4.w, b4.w);
    if (ADD) {
        float4 bvv = ((const float4*)base)[i];
        r.x += bvv.x; r.y += bvv.y; r.z += bvv.z; r.w += bvv.w;
    }
    if (RELU) {
        r.x = fmaxf(r.x, 0.f); r.y = fmaxf(r.y, 0.f);
        r.z = fmaxf(r.z, 0.f); r.w = fmaxf(r.w, 0.f);
    }
    ((float4*)out)[i] = r;
}

// ---------------- conv3 weight packer: [3][256][8] -> [256][32] (+ padded bias)
__global__ void pack_conv3_kernel(const float* __restrict__ w, const float* __restrict__ bias,
                                  float* __restrict__ wpack, float* __restrict__ bpack)
{
    int t = blockIdx.x * 256 + threadIdx.x;
    if (t < 256 * 32) {
        int ki = t / 32, c = t % 32;
        int j = c / 8, o = c % 8;
        wpack[t] = (j < 3) ? w[(size_t)j * 2048 + ki * 8 + o] : 0.f;
    }
    if (t < 32) bpack[t] = (t < 8) ? bias[t] : 0.f;
}

// ---------------- conv3 tail helpers
__global__ void combine_kernel(float* __restrict__ e, const float* __restrict__ z1,
                               const float* __restrict__ t)
{
    int i = blockIdx.x * 256 + threadIdx.x;
    e[i] = fmaf(2.f, t[i], z1[i]);
}

__global__ void final_add_kernel(float* __restrict__ out, const float* __restrict__ z0,
                                 const float* __restrict__ z2, const float* __restrict__ s)
{
    int i = blockIdx.x * 256 + threadIdx.x;
    out[i] = z0[i] - z2[i] + s[i];
}

extern "C" void kernel_launch(void* const* d_in, const int* in_sizes, int n_in,
                              void* d_out, int out_size, void* d_ws, size_t ws_size,
                              hipStream_t stream)
{
    const float* x       = (const float*)d_in[0];
    const int*   col     = (const int*)  d_in[2];
    const float* eval_   = (const float*)d_in[3];
    const float* conv1_w = (const float*)d_in[4];
    const float* conv1_b = (const float*)d_in[5];
    const float* bn1_g   = (const float*)d_in[6];
    const float* bn1_b   = (const float*)d_in[7];
    const float* conv2_w = (const float*)d_in[8];
    const float* conv2_b = (const float*)d_in[9];
    const float* bn2_g   = (const float*)d_in[10];
    const float* bn2_b   = (const float*)d_in[11];
    const float* bt_c1w  = (const float*)d_in[12];
    const float* bt_c1b  = (const float*)d_in[13];
    const float* bt_c2w  = (const float*)d_in[14];
    const float* bt_c2b  = (const float*)d_in[15];
    const float* bt_c3w  = (const float*)d_in[16];
    const float* bt_c3b  = (const float*)d_in[17];
    const float* btbn1g  = (const float*)d_in[18];
    const float* btbn1b  = (const float*)d_in[19];
    const float* btbn2g  = (const float*)d_in[20];
    const float* btbn2b  = (const float*)d_in[21];
    const float* btbn3g  = (const float*)d_in[22];
    const float* btbn3b  = (const float*)d_in[23];
    const float* conv3_w = (const float*)d_in[24];
    const float* conv3_b = (const float*)d_in[25];
    float* out = (float*)d_out;

    float* ws = (float*)d_ws;
    float* h2    = ws;                         // BV*256
    float* y3    = h2 + (size_t)BV * 256;      // BV*256 (aliased as stats partial)
    float* t64a  = y3 + (size_t)BV * 256;      // BV*64
    float* t64b  = t64a + (size_t)BV * 64;     // BV*64
    float* t64c  = t64b + (size_t)BV * 64;     // BV*64
    float* t64d  = t64c + (size_t)BV * 64;     // BV*64
    float* aarr  = t64d + (size_t)BV * 64;     // 11*256
    float* barr  = aarr + 11 * 256;            // 11*256
    float* wpack = barr + 11 * 256;            // 256*32
    float* bpack = wpack + 256 * 32;           // 32
    float2* partY = (float2*)y3;               // partial when y3 is dead
    float2* partC = (float2*)t64c;             // partial for cheb3 (y3 being written)

    const float invN = 1.f / (float)BV;
    const int NGB = BV / 32;                   // 1536 GEMM blocks

    // ---------- Stage A: conv1 (8 -> 64), K=3 ----------
    spmm8_kernel<false><<<BV * 8 / 256, 256, 0, stream>>>(t64a, x, nullptr, eval_, col);
    spmm8_kernel<true ><<<BV * 8 / 256, 256, 0, stream>>>(t64b, t64a, x, eval_, col);
    gemm_lds_kernel<64, 24, 8, 4, 16, 16, 2, 3, true, false, true, false>
        <<<NGB, 256, 0, stream>>>(x, t64a, t64b, conv1_w, conv1_b, nullptr, nullptr, t64c, partY);
    bn_finalize_kernel<<<64, 256, 0, stream>>>(partY, bn1_g, bn1_b, aarr, barr, invN, NGB);

    // ---------- Stage B: conv2 (64 -> 256), K=3, x0-BN fused ----------
    spmm64_kernel<false, true, false><<<BV * 16 / 256, 256, 0, stream>>>(t64a, t64c, nullptr, eval_, col, aarr, barr);
    spmm64_kernel<true, false, true ><<<BV * 16 / 256, 256, 0, stream>>>(t64b, t64a, t64c, eval_, col, aarr, barr);
    gemm_lds_kernel<256, 192, 64, 8, 32, 8, 4, 3, true, true, true, false>
        <<<NGB, 256, 0, stream>>>(t64c, t64a, t64b, conv2_w, conv2_b, aarr, barr, h2, partY);
    bn_finalize_kernel<<<256, 256, 0, stream>>>(partY, bn2_g, bn2_b, aarr + 256, barr + 256, invN, NGB);
    bn_apply_kernel<256, true, false><<<BV, 256, 0, stream>>>(h2, h2, nullptr, aarr + 256, barr + 256);

    // ---------- Stage C: 3 bottlenecks ----------
    for (int i = 0; i < 3; ++i) {
        float* aA = aarr + (2 + i * 3) * 256; float* bA = barr + (2 + i * 3) * 256;
        float* aB = aarr + (3 + i * 3) * 256; float* bB = barr + (3 + i * 3) * 256;
        float* aC = aarr + (4 + i * 3) * 256; float* bC = barr + (4 + i * 3) * 256;

        // cheb1: K=1, 256->64, stats fused
        gemm_lds_kernel<64, 256, 256, 4, 16, 16, 2, 1, true, false, true, false>
            <<<NGB, 256, 0, stream>>>(h2, nullptr, nullptr,
                                      bt_c1w + (size_t)i * 256 * 64, bt_c1b + i * 64,
                                      nullptr, nullptr, t64c, partY);
        bn_finalize_kernel<<<64, 256, 0, stream>>>(partY, btbn1g + i * 64, btbn1b + i * 64, aA, bA, invN, NGB);

        // cheb2: K=3, 64->64; BN1 fused into gathers and x0-staging
        spmm64_kernel<false, true, false><<<BV * 16 / 256, 256, 0, stream>>>(t64a, t64c, nullptr, eval_, col, aA, bA);
        spmm64_kernel<true, false, true ><<<BV * 16 / 256, 256, 0, stream>>>(t64b, t64a, t64c, eval_, col, aA, bA);
        gemm_lds_kernel<64, 192, 64, 4, 16, 16, 2, 3, true, true, true, false>
            <<<NGB, 256, 0, stream>>>(t64c, t64a, t64b,
                                      bt_c2w + (size_t)i * 3 * 64 * 64, bt_c2b + i * 64,
                                      aA, bA, t64d, partY);
        bn_finalize_kernel<<<64, 256, 0, stream>>>(partY, btbn2g + i * 64, btbn2b + i * 64, aB, bB, invN, NGB);

        // cheb3: K=1, 64->256; BN2 fused into x0-staging; stats partial -> t64c
        gemm_lds_kernel<256, 64, 64, 8, 32, 8, 4, 1, true, true, true, false>
            <<<NGB, 256, 0, stream>>>(t64d, nullptr, nullptr,
                                      bt_c3w + (size_t)i * 64 * 256, bt_c3b + i * 256,
                                      aB, bB, y3, partC);
        bn_finalize_kernel<<<256, 256, 0, stream>>>(partC, btbn3g + i * 256, btbn3b + i * 256, aC, bC, invN, NGB);
        // BN3 apply + residual add into h2
        bn_apply_kernel<256, false, true><<<BV, 256, 0, stream>>>(h2, y3, h2, aC, bC);
    }

    // ---------- Stage D: conv3 (256 -> 8), K=3, commuted: out = z0 - z2 + L(z1 + 2*L*z2) ----------
    float* z0 = t64a;
    float* z1 = z0 + (size_t)BV * 8;
    float* z2 = z1 + (size_t)BV * 8;
    float* tt = z2 + (size_t)BV * 8;
    float* ee = tt + (size_t)BV * 8;
    float* sb = ee + (size_t)BV * 8;

    pack_conv3_kernel<<<32, 256, 0, stream>>>(conv3_w, conv3_b, wpack, bpack);
    gemm_lds_kernel<32, 256, 256, 4, 8, 32, 1, 1, false, false, true, true>
        <<<NGB, 256, 0, stream>>>(h2, nullptr, nullptr, wpack, bpack, nullptr, nullptr, z0, nullptr);

    spmm8_kernel<false><<<BV * 8 / 256, 256, 0, stream>>>(tt, z2, nullptr, eval_, col);
    combine_kernel<<<BV * 8 / 256, 256, 0, stream>>>(ee, z1, tt);
    spmm8_kernel<false><<<BV * 8 / 256, 256, 0, stream>>>(sb, ee, nullptr, eval_, col);
    final_add_kernel<<<BV * 8 / 256, 256, 0, stream>>>(out, z0, z2, sb);

    (void)in_sizes; (void)n_in; (void)out_size; (void)ws_size;
}

// Round 6
// 902.506 us; speedup vs baseline: 2.3173x; 1.2791x over previous
//
#include <hip/hip_runtime.h>

static constexpr int NBRS = 21;
static constexpr int Nv   = 12288;
static constexpr int BV   = 4 * Nv;            // 49152 rows
static constexpr float BN_EPS = 1e-5f;

// ---------------- SPMM (C=8, scalar)
template<bool CHEB2>
__global__ void spmm8_kernel(float* __restrict__ y, const float* __restrict__ x,
                             const float* __restrict__ x0,
                             const float* __restrict__ val, const int* __restrict__ col)
{
    int idx = blockIdx.x * 256 + threadIdx.x;
    int c = idx % 8;
    int v = (idx / 8) % Nv;
    int b = idx / (8 * Nv);
    int e0 = v * NBRS;
    float acc = 0.f;
    #pragma unroll
    for (int j = 0; j < NBRS; ++j) {
        int u = col[e0 + j];
        acc = fmaf(val[e0 + j], x[((size_t)b * Nv + u) * 8 + c], acc);
    }
    if (CHEB2) y[idx] = 2.f * acc - x0[idx];
    else       y[idx] = acc;
}

// ---------------- SPMM C=64, float4, optional fused BN+relu on gather and/or x0
template<bool CHEB2, bool BNG, bool BNX0>
__global__ __launch_bounds__(256)
void spmm64_kernel(float* __restrict__ y, const float* __restrict__ x,
                   const float* __restrict__ x0,
                   const float* __restrict__ val, const int* __restrict__ col,
                   const float* __restrict__ bn_a, const float* __restrict__ bn_b)
{
    int idx = blockIdx.x * 256 + threadIdx.x;   // over BV*16
    int q = idx % 16;
    int v = (idx / 16) % Nv;
    int b = idx / (16 * Nv);
    int e0 = v * NBRS;
    const float4* x4 = (const float4*)x;
    float4 a4, b4;
    if (BNG || (CHEB2 && BNX0)) {
        a4 = ((const float4*)bn_a)[q];
        b4 = ((const float4*)bn_b)[q];
    }
    float4 acc = {0.f, 0.f, 0.f, 0.f};
    #pragma unroll
    for (int j = 0; j < NBRS; ++j) {
        int u = col[e0 + j];
        float a = val[e0 + j];
        float4 xv = x4[(size_t)(b * Nv + u) * 16 + q];
        if (BNG) {
            xv.x = fmaxf(fmaf(xv.x, a4.x, b4.x), 0.f);
            xv.y = fmaxf(fmaf(xv.y, a4.y, b4.y), 0.f);
            xv.z = fmaxf(fmaf(xv.z, a4.z, b4.z), 0.f);
            xv.w = fmaxf(fmaf(xv.w, a4.w, b4.w), 0.f);
        }
        acc.x = fmaf(a, xv.x, acc.x);
        acc.y = fmaf(a, xv.y, acc.y);
        acc.z = fmaf(a, xv.z, acc.z);
        acc.w = fmaf(a, xv.w, acc.w);
    }
    if (CHEB2) {
        float4 pv = ((const float4*)x0)[idx];
        if (BNX0) {
            pv.x = fmaxf(fmaf(pv.x, a4.x, b4.x), 0.f);
            pv.y = fmaxf(fmaf(pv.y, a4.y, b4.y), 0.f);
            pv.z = fmaxf(fmaf(pv.z, a4.z, b4.z), 0.f);
            pv.w = fmaxf(fmaf(pv.w, a4.w, b4.w), 0.f);
        }
        acc.x = 2.f * acc.x - pv.x;
        acc.y = 2.f * acc.y - pv.y;
        acc.z = 2.f * acc.z - pv.z;
        acc.w = 2.f * acc.w - pv.w;
    }
    ((float4*)y)[idx] = acc;
}

// ---------------- LDS-staged GEMM, K-chunked, float4 LDS reads.
// out[m,o] = sum_ki x[m,ki] * w[ki,o] (+bias); optional fused BN+relu on the
// x0 portion at staging; fused BN-stats in epilogue (partial: [FOUT][grid]).
template<int FOUT, int KFIN, int KCH, int FIN, int TO, int OTHR, int RGRP, int RPG,
         int NSRC, bool STATS, bool BN0, bool HAS_BIAS, bool PACKOUT>
__global__ __launch_bounds__(OTHR * RGRP)
void gemm_lds_kernel(const float* __restrict__ x0, const float* __restrict__ x1,
                     const float* __restrict__ x2,
                     const float* __restrict__ w, const float* __restrict__ bias,
                     const float* __restrict__ bn_a, const float* __restrict__ bn_b,
                     float* __restrict__ out, float2* __restrict__ partial)
{
    constexpr int THREADS = OTHR * RGRP;
    constexpr int ROWS = RGRP * RPG;
    constexpr int NCH = KFIN / KCH;
    constexpr int LDK = KCH + 4;                        // pad: bank-spread + f4 align
    constexpr size_t XS_B  = (size_t)ROWS * LDK * 4;
    constexpr size_t RED_B = STATS ? (size_t)RGRP * (FOUT + 1) * 8 : 0;
    constexpr size_t SMEM  = XS_B > RED_B ? XS_B : RED_B;
    __shared__ __align__(16) char smem[SMEM];
    float* xs = (float*)smem;

    const int tid = threadIdx.x;
    const int m0 = blockIdx.x * ROWS;
    const int othr = tid % OTHR;
    const int grp  = tid / OTHR;
    const int o0 = othr * TO;
    const int r0 = grp * RPG;

    float acc[RPG][TO];
    #pragma unroll
    for (int r = 0; r < RPG; ++r)
        #pragma unroll
        for (int t = 0; t < TO; ++t) acc[r][t] = 0.f;

    for (int kc = 0; kc < NCH; ++kc) {
        if (kc) __syncthreads();                        // xs reuse hazard
        // ---- stage x chunk (coalesced float4), optional BN+relu on x0 part
        constexpr int NF4 = ROWS * KCH / 4;
        for (int f = tid; f < NF4; f += THREADS) {
            const int r   = f / (KCH / 4);
            const int kil = (f % (KCH / 4)) * 4;
            const int kig = kc * KCH + kil;
            const float* src; int i; int kk;
            if constexpr (NSRC == 1) { src = x0; i = kig; kk = 0; }
            else { kk = kig / FIN; i = kig % FIN; src = (kk == 0) ? x0 : (kk == 1 ? x1 : x2); }
            float4 v = *(const float4*)(src + (size_t)(m0 + r) * FIN + i);
            if constexpr (BN0) {
                if (NSRC == 1 || kk == 0) {
                    const float4 a4 = *(const float4*)(bn_a + i);
                    const float4 b4 = *(const float4*)(bn_b + i);
                    v.x = fmaxf(fmaf(v.x, a4.x, b4.x), 0.f);
                    v.y = fmaxf(fmaf(v.y, a4.y, b4.y), 0.f);
                    v.z = fmaxf(fmaf(v.z, a4.z, b4.z), 0.f);
                    v.w = fmaxf(fmaf(v.w, a4.w, b4.w), 0.f);
                }
            }
            *(float4*)(xs + (size_t)r * LDK + kil) = v;
        }
        __syncthreads();

        // ---- compute chunk
        const float* wc = w + (size_t)kc * KCH * FOUT;
        #pragma unroll 2
        for (int k4 = 0; k4 < KCH / 4; ++k4) {
            const int ki = k4 * 4;
            float4 xv[RPG];
            #pragma unroll
            for (int r = 0; r < RPG; ++r)
                xv[r] = *(const float4*)(xs + (size_t)(r0 + r) * LDK + ki);
            #pragma unroll
            for (int j = 0; j < 4; ++j) {
                float wv[TO];
                {
                    const float4 wa = *(const float4*)(wc + (size_t)(ki + j) * FOUT + o0);
                    wv[0] = wa.x; wv[1] = wa.y; wv[2] = wa.z; wv[3] = wa.w;
                    if constexpr (TO == 8) {
                        const float4 wb = *(const float4*)(wc + (size_t)(ki + j) * FOUT + o0 + 4);
                        wv[4] = wb.x; wv[5] = wb.y; wv[6] = wb.z; wv[7] = wb.w;
                    }
                }
                #pragma unroll
                for (int r = 0; r < RPG; ++r) {
                    const float xx = (j == 0) ? xv[r].x : (j == 1) ? xv[r].y
                                   : (j == 2) ? xv[r].z : xv[r].w;
                    #pragma unroll
                    for (int t = 0; t < TO; ++t) acc[r][t] = fmaf(xx, wv[t], acc[r][t]);
                }
            }
        }
    }
    __syncthreads();   // xs dead; smem reusable for stats reduce

    float bv[TO];
    if constexpr (HAS_BIAS) {
        const float4 ba = *(const float4*)(bias + o0);
        bv[0] = ba.x; bv[1] = ba.y; bv[2] = ba.z; bv[3] = ba.w;
        if constexpr (TO == 8) {
            const float4 bb = *(const float4*)(bias + o0 + 4);
            bv[4] = bb.x; bv[5] = bb.y; bv[6] = bb.z; bv[7] = bb.w;
        }
    } else {
        #pragma unroll
        for (int t = 0; t < TO; ++t) bv[t] = 0.f;
    }

    float s[TO], q[TO];
    #pragma unroll
    for (int t = 0; t < TO; ++t) { s[t] = 0.f; q[t] = 0.f; }

    #pragma unroll
    for (int r = 0; r < RPG; ++r) {
        float v[TO];
        #pragma unroll
        for (int t = 0; t < TO; ++t) {
            v[t] = acc[r][t] + bv[t];
            if constexpr (STATS) { s[t] += v[t]; q[t] = fmaf(v[t], v[t], q[t]); }
        }
        const int m = m0 + r0 + r;
        if constexpr (PACKOUT) {
            // TO==4: othr>>1 selects z_j (0..2, 3 dummy), othr&1 selects col half
            const int zj = othr >> 1, half = othr & 1;
            if (zj < 3)
                *(float4*)(out + ((size_t)zj * BV + m) * 8 + half * 4) =
                    make_float4(v[0], v[1], v[2], v[3]);
        } else {
            float* dst = out + (size_t)m * FOUT + o0;
            *(float4*)dst = make_float4(v[0], v[1], v[2], v[3]);
            if constexpr (TO == 8)
                *(float4*)(dst + 4) = make_float4(v[4], v[5], v[6], v[7]);
        }
    }

    if constexpr (STATS) {
        float2* red = (float2*)smem;              // [RGRP][FOUT+1]
        #pragma unroll
        for (int t = 0; t < TO; ++t)
            red[(size_t)grp * (FOUT + 1) + o0 + t] = make_float2(s[t], q[t]);
        __syncthreads();
        for (int c = tid; c < FOUT; c += THREADS) {
            float rs = 0.f, rq = 0.f;
            #pragma unroll 4
            for (int g = 0; g < RGRP; ++g) {
                const float2 p = red[(size_t)g * (FOUT + 1) + c];
                rs += p.x; rq += p.y;
            }
            partial[(size_t)c * gridDim.x + blockIdx.x] = make_float2(rs, rq);
        }
    }
}

// ---------------- BN finalize: one block per channel, coalesced over [C][nblk]
__global__ __launch_bounds__(256)
void bn_finalize_kernel(const float2* __restrict__ partial,
                        const float* __restrict__ g, const float* __restrict__ b,
                        float* __restrict__ a_out, float* __restrict__ b_out,
                        float invN, int nblk)
{
    __shared__ float2 red[4];
    const int c = blockIdx.x;
    const float2* p = partial + (size_t)c * nblk;
    float s = 0.f, ss = 0.f;
    for (int k = threadIdx.x; k < nblk; k += 256) {
        const float2 v = p[k];
        s += v.x; ss += v.y;
    }
    #pragma unroll
    for (int off = 32; off > 0; off >>= 1) {
        s  += __shfl_down(s, off);
        ss += __shfl_down(ss, off);
    }
    if ((threadIdx.x & 63) == 0) red[threadIdx.x >> 6] = make_float2(s, ss);
    __syncthreads();
    if (threadIdx.x == 0) {
        float ts = 0.f, tq = 0.f;
        #pragma unroll
        for (int i = 0; i < 4; ++i) { ts += red[i].x; tq += red[i].y; }
        const float m = ts * invN;
        const float var = tq * invN - m * m;
        const float a = g[c] * rsqrtf(var + BN_EPS);
        a_out[c] = a;
        b_out[c] = b[c] - m * a;
    }
}

// ---------------- BN apply (float4), for C=256 tensors only
template<int C, bool RELU, bool ADD>
__global__ __launch_bounds__(256)
void bn_apply_kernel(float* __restrict__ out, const float* __restrict__ x,
                     const float* __restrict__ base,
                     const float* __restrict__ bn_a, const float* __restrict__ bn_b)
{
    int i = blockIdx.x * 256 + threadIdx.x;   // float4 index
    float4 v = ((const float4*)x)[i];
    int c0 = (i * 4) % C;
    float4 a4 = *reinterpret_cast<const float4*>(bn_a + c0);
    float4 b4 = *reinterpret_cast<const float4*>(bn_b + c0);
    float4 r;
    r.x = fmaf(v.x, a4.x, b4.x);
    r.y = fmaf(v.y, a4.y, b4.y);
    r.z = fmaf(v.z, a4.z, b4.z);
    r.w = fmaf(v.w, a4.w, b4.w);
    if (ADD) {
        float4 bvv = ((const float4*)base)[i];
        r.x += bvv.x; r.y += bvv.y; r.z += bvv.z; r.w += bvv.w;
    }
    if (RELU) {
        r.x = fmaxf(r.x, 0.f); r.y = fmaxf(r.y, 0.f);
        r.z = fmaxf(r.z, 0.f); r.w = fmaxf(r.w, 0.f);
    }
    ((float4*)out)[i] = r;
}

// ---------------- conv3 weight packer: [3][256][8] -> [256][32] (+ padded bias)
__global__ void pack_conv3_kernel(const float* __restrict__ w, const float* __restrict__ bias,
                                  float* __restrict__ wpack, float* __restrict__ bpack)
{
    int t = blockIdx.x * 256 + threadIdx.x;
    if (t < 256 * 32) {
        int ki = t / 32, c = t % 32;
        int j = c / 8, o = c % 8;
        wpack[t] = (j < 3) ? w[(size_t)j * 2048 + ki * 8 + o] : 0.f;
    }
    if (t < 32) bpack[t] = (t < 8) ? bias[t] : 0.f;
}

// ---------------- conv3 tail helpers
__global__ void combine_kernel(float* __restrict__ e, const float* __restrict__ z1,
                               const float* __restrict__ t)
{
    int i = blockIdx.x * 256 + threadIdx.x;
    e[i] = fmaf(2.f, t[i], z1[i]);
}

__global__ void final_add_kernel(float* __restrict__ out, const float* __restrict__ z0,
                                 const float* __restrict__ z2, const float* __restrict__ s)
{
    int i = blockIdx.x * 256 + threadIdx.x;
    out[i] = z0[i] - z2[i] + s[i];
}

extern "C" void kernel_launch(void* const* d_in, const int* in_sizes, int n_in,
                              void* d_out, int out_size, void* d_ws, size_t ws_size,
                              hipStream_t stream)
{
    const float* x       = (const float*)d_in[0];
    const int*   col     = (const int*)  d_in[2];
    const float* eval_   = (const float*)d_in[3];
    const float* conv1_w = (const float*)d_in[4];
    const float* conv1_b = (const float*)d_in[5];
    const float* bn1_g   = (const float*)d_in[6];
    const float* bn1_b   = (const float*)d_in[7];
    const float* conv2_w = (const float*)d_in[8];
    const float* conv2_b = (const float*)d_in[9];
    const float* bn2_g   = (const float*)d_in[10];
    const float* bn2_b   = (const float*)d_in[11];
    const float* bt_c1w  = (const float*)d_in[12];
    const float* bt_c1b  = (const float*)d_in[13];
    const float* bt_c2w  = (const float*)d_in[14];
    const float* bt_c2b  = (const float*)d_in[15];
    const float* bt_c3w  = (const float*)d_in[16];
    const float* bt_c3b  = (const float*)d_in[17];
    const float* btbn1g  = (const float*)d_in[18];
    const float* btbn1b  = (const float*)d_in[19];
    const float* btbn2g  = (const float*)d_in[20];
    const float* btbn2b  = (const float*)d_in[21];
    const float* btbn3g  = (const float*)d_in[22];
    const float* btbn3b  = (const float*)d_in[23];
    const float* conv3_w = (const float*)d_in[24];
    const float* conv3_b = (const float*)d_in[25];
    float* out = (float*)d_out;

    float* ws = (float*)d_ws;
    float* h2    = ws;                         // BV*256
    float* y3    = h2 + (size_t)BV * 256;      // BV*256 (aliased as stats partial)
    float* t64a  = y3 + (size_t)BV * 256;      // BV*64
    float* t64b  = t64a + (size_t)BV * 64;     // BV*64
    float* t64c  = t64b + (size_t)BV * 64;     // BV*64
    float* t64d  = t64c + (size_t)BV * 64;     // BV*64
    float* aarr  = t64d + (size_t)BV * 64;     // 11*256
    float* barr  = aarr + 11 * 256;            // 11*256
    float* wpack = barr + 11 * 256;            // 256*32
    float* bpack = wpack + 256 * 32;           // 32
    float2* partY = (float2*)y3;               // partial when y3 is dead
    float2* partC = (float2*)t64c;             // partial for cheb3 (y3 being written)

    const float invN = 1.f / (float)BV;

    // ---------- Stage A: conv1 (8 -> 64), K=3 ----------
    spmm8_kernel<false><<<BV * 8 / 256, 256, 0, stream>>>(t64a, x, nullptr, eval_, col);
    spmm8_kernel<true ><<<BV * 8 / 256, 256, 0, stream>>>(t64b, t64a, x, eval_, col);
    gemm_lds_kernel<64, 24, 24, 8, 4, 16, 16, 4, 3, true, false, true, false>
        <<<BV / 64, 256, 0, stream>>>(x, t64a, t64b, conv1_w, conv1_b, nullptr, nullptr, t64c, partY);
    bn_finalize_kernel<<<64, 256, 0, stream>>>(partY, bn1_g, bn1_b, aarr, barr, invN, BV / 64);

    // ---------- Stage B: conv2 (64 -> 256), K=3, x0-BN fused ----------
    spmm64_kernel<false, true, false><<<BV * 16 / 256, 256, 0, stream>>>(t64a, t64c, nullptr, eval_, col, aarr, barr);
    spmm64_kernel<true, false, true ><<<BV * 16 / 256, 256, 0, stream>>>(t64b, t64a, t64c, eval_, col, aarr, barr);
    gemm_lds_kernel<256, 192, 96, 64, 4, 64, 4, 8, 3, true, true, true, false>
        <<<BV / 32, 256, 0, stream>>>(t64c, t64a, t64b, conv2_w, conv2_b, aarr, barr, h2, partY);
    bn_finalize_kernel<<<256, 256, 0, stream>>>(partY, bn2_g, bn2_b, aarr + 256, barr + 256, invN, BV / 32);
    bn_apply_kernel<256, true, false><<<BV, 256, 0, stream>>>(h2, h2, nullptr, aarr + 256, barr + 256);

    // ---------- Stage C: 3 bottlenecks ----------
    for (int i = 0; i < 3; ++i) {
        float* aA = aarr + (2 + i * 3) * 256; float* bA = barr + (2 + i * 3) * 256;
        float* aB = aarr + (3 + i * 3) * 256; float* bB = barr + (3 + i * 3) * 256;
        float* aC = aarr + (4 + i * 3) * 256; float* bC = barr + (4 + i * 3) * 256;

        // cheb1: K=1, 256->64, K-chunked, stats fused
        gemm_lds_kernel<64, 256, 128, 256, 4, 16, 16, 4, 1, true, false, true, false>
            <<<BV / 64, 256, 0, stream>>>(h2, nullptr, nullptr,
                                          bt_c1w + (size_t)i * 256 * 64, bt_c1b + i * 64,
                                          nullptr, nullptr, t64c, partY);
        bn_finalize_kernel<<<64, 256, 0, stream>>>(partY, btbn1g + i * 64, btbn1b + i * 64, aA, bA, invN, BV / 64);

        // cheb2: K=3, 64->64; BN1 fused into gathers and x0-staging
        spmm64_kernel<false, true, false><<<BV * 16 / 256, 256, 0, stream>>>(t64a, t64c, nullptr, eval_, col, aA, bA);
        spmm64_kernel<true, false, true ><<<BV * 16 / 256, 256, 0, stream>>>(t64b, t64a, t64c, eval_, col, aA, bA);
        gemm_lds_kernel<64, 192, 96, 64, 4, 16, 16, 4, 3, true, true, true, false>
            <<<BV / 64, 256, 0, stream>>>(t64c, t64a, t64b,
                                          bt_c2w + (size_t)i * 3 * 64 * 64, bt_c2b + i * 64,
                                          aA, bA, t64d, partY);
        bn_finalize_kernel<<<64, 256, 0, stream>>>(partY, btbn2g + i * 64, btbn2b + i * 64, aB, bB, invN, BV / 64);

        // cheb3: K=1, 64->256; BN2 fused into x0-staging; stats partial -> t64c
        gemm_lds_kernel<256, 64, 64, 64, 4, 64, 4, 8, 1, true, true, true, false>
            <<<BV / 32, 256, 0, stream>>>(t64d, nullptr, nullptr,
                                          bt_c3w + (size_t)i * 64 * 256, bt_c3b + i * 256,
                                          aB, bB, y3, partC);
        bn_finalize_kernel<<<256, 256, 0, stream>>>(partC, btbn3g + i * 256, btbn3b + i * 256, aC, bC, invN, BV / 32);
        // BN3 apply + residual add into h2
        bn_apply_kernel<256, false, true><<<BV, 256, 0, stream>>>(h2, y3, h2, aC, bC);
    }

    // ---------- Stage D: conv3 (256 -> 8), K=3, commuted: out = z0 - z2 + L(z1 + 2*L*z2) ----------
    float* z0 = t64a;
    float* z1 = z0 + (size_t)BV * 8;
    float* z2 = z1 + (size_t)BV * 8;
    float* tt = z2 + (size_t)BV * 8;
    float* ee = tt + (size_t)BV * 8;
    float* sb = ee + (size_t)BV * 8;

    pack_conv3_kernel<<<32, 256, 0, stream>>>(conv3_w, conv3_b, wpack, bpack);
    gemm_lds_kernel<32, 256, 128, 256, 4, 8, 32, 2, 1, false, false, true, true>
        <<<BV / 64, 256, 0, stream>>>(h2, nullptr, nullptr, wpack, bpack, nullptr, nullptr, z0, nullptr);

    spmm8_kernel<false><<<BV * 8 / 256, 256, 0, stream>>>(tt, z2, nullptr, eval_, col);
    combine_kernel<<<BV * 8 / 256, 256, 0, stream>>>(ee, z1, tt);
    spmm8_kernel<false><<<BV * 8 / 256, 256, 0, stream>>>(sb, ee, nullptr, eval_, col);
    final_add_kernel<<<BV * 8 / 256, 256, 0, stream>>>(out, z0, z2, sb);

    (void)in_sizes; (void)n_in; (void)out_size; (void)ws_size;
}

// Round 7
// 678.947 us; speedup vs baseline: 3.0803x; 1.3293x over previous
//
#include <hip/hip_runtime.h>

static constexpr int NBRS = 21;
static constexpr int Nv   = 12288;
static constexpr int BV   = 4 * Nv;            // 49152 rows
static constexpr float BN_EPS = 1e-5f;

// ---------------- SPMM (C=8, scalar)
template<bool CHEB2>
__global__ void spmm8_kernel(float* __restrict__ y, const float* __restrict__ x,
                             const float* __restrict__ x0,
                             const float* __restrict__ val, const int* __restrict__ col)
{
    int idx = blockIdx.x * 256 + threadIdx.x;
    int c = idx % 8;
    int v = (idx / 8) % Nv;
    int b = idx / (8 * Nv);
    int e0 = v * NBRS;
    float acc = 0.f;
    #pragma unroll
    for (int j = 0; j < NBRS; ++j) {
        int u = col[e0 + j];
        acc = fmaf(val[e0 + j], x[((size_t)b * Nv + u) * 8 + c], acc);
    }
    if (CHEB2) y[idx] = 2.f * acc - x0[idx];
    else       y[idx] = acc;
}

// ---------------- SPMM C=64, float4, optional fused BN+relu on gather and/or x0
template<bool CHEB2, bool BNG, bool BNX0>
__global__ __launch_bounds__(256)
void spmm64_kernel(float* __restrict__ y, const float* __restrict__ x,
                   const float* __restrict__ x0,
                   const float* __restrict__ val, const int* __restrict__ col,
                   const float* __restrict__ bn_a, const float* __restrict__ bn_b)
{
    int idx = blockIdx.x * 256 + threadIdx.x;   // over BV*16
    int q = idx % 16;
    int v = (idx / 16) % Nv;
    int b = idx / (16 * Nv);
    int e0 = v * NBRS;
    const float4* x4 = (const float4*)x;
    float4 a4, b4;
    if (BNG || (CHEB2 && BNX0)) {
        a4 = ((const float4*)bn_a)[q];
        b4 = ((const float4*)bn_b)[q];
    }
    float4 acc = {0.f, 0.f, 0.f, 0.f};
    #pragma unroll
    for (int j = 0; j < NBRS; ++j) {
        int u = col[e0 + j];
        float a = val[e0 + j];
        float4 xv = x4[(size_t)(b * Nv + u) * 16 + q];
        if (BNG) {
            xv.x = fmaxf(fmaf(xv.x, a4.x, b4.x), 0.f);
            xv.y = fmaxf(fmaf(xv.y, a4.y, b4.y), 0.f);
            xv.z = fmaxf(fmaf(xv.z, a4.z, b4.z), 0.f);
            xv.w = fmaxf(fmaf(xv.w, a4.w, b4.w), 0.f);
        }
        acc.x = fmaf(a, xv.x, acc.x);
        acc.y = fmaf(a, xv.y, acc.y);
        acc.z = fmaf(a, xv.z, acc.z);
        acc.w = fmaf(a, xv.w, acc.w);
    }
    if (CHEB2) {
        float4 pv = ((const float4*)x0)[idx];
        if (BNX0) {
            pv.x = fmaxf(fmaf(pv.x, a4.x, b4.x), 0.f);
            pv.y = fmaxf(fmaf(pv.y, a4.y, b4.y), 0.f);
            pv.z = fmaxf(fmaf(pv.z, a4.z, b4.z), 0.f);
            pv.w = fmaxf(fmaf(pv.w, a4.w, b4.w), 0.f);
        }
        acc.x = 2.f * acc.x - pv.x;
        acc.y = 2.f * acc.y - pv.y;
        acc.z = 2.f * acc.z - pv.z;
        acc.w = 2.f * acc.w - pv.w;
    }
    ((float4*)y)[idx] = acc;
}

// ---------------- LDS-staged GEMM, K-chunked, float4 LDS reads.
// out[m,o] = sum_ki x[m,ki] * w[ki,o] (+bias); optional fused BN+relu on the
// x0 portion at staging; fused BN-stats in epilogue (partial: [FOUT][grid]).
template<int FOUT, int KFIN, int KCH, int FIN, int TO, int OTHR, int RGRP, int RPG,
         int NSRC, bool STATS, bool BN0, bool HAS_BIAS, bool PACKOUT>
__global__ __launch_bounds__(OTHR * RGRP)
void gemm_lds_kernel(const float* __restrict__ x0, const float* __restrict__ x1,
                     const float* __restrict__ x2,
                     const float* __restrict__ w, const float* __restrict__ bias,
                     const float* __restrict__ bn_a, const float* __restrict__ bn_b,
                     float* __restrict__ out, float2* __restrict__ partial)
{
    constexpr int THREADS = OTHR * RGRP;
    constexpr int ROWS = RGRP * RPG;
    constexpr int NCH = KFIN / KCH;
    constexpr int LDK = KCH + 4;                        // pad: bank-spread + f4 align
    constexpr size_t XS_B  = (size_t)ROWS * LDK * 4;
    constexpr size_t RED_B = STATS ? (size_t)RGRP * (FOUT + 1) * 8 : 0;
    constexpr size_t SMEM  = XS_B > RED_B ? XS_B : RED_B;
    __shared__ __align__(16) char smem[SMEM];
    float* xs = (float*)smem;

    const int tid = threadIdx.x;
    const int m0 = blockIdx.x * ROWS;
    const int othr = tid % OTHR;
    const int grp  = tid / OTHR;
    const int o0 = othr * TO;
    const int r0 = grp * RPG;

    float acc[RPG][TO];
    #pragma unroll
    for (int r = 0; r < RPG; ++r)
        #pragma unroll
        for (int t = 0; t < TO; ++t) acc[r][t] = 0.f;

    for (int kc = 0; kc < NCH; ++kc) {
        if (kc) __syncthreads();                        // xs reuse hazard
        // ---- stage x chunk (coalesced float4), optional BN+relu on x0 part
        constexpr int NF4 = ROWS * KCH / 4;
        for (int f = tid; f < NF4; f += THREADS) {
            const int r   = f / (KCH / 4);
            const int kil = (f % (KCH / 4)) * 4;
            const int kig = kc * KCH + kil;
            const float* src; int i; int kk;
            if constexpr (NSRC == 1) { src = x0; i = kig; kk = 0; }
            else { kk = kig / FIN; i = kig % FIN; src = (kk == 0) ? x0 : (kk == 1 ? x1 : x2); }
            float4 v = *(const float4*)(src + (size_t)(m0 + r) * FIN + i);
            if constexpr (BN0) {
                if (NSRC == 1 || kk == 0) {
                    const float4 a4 = *(const float4*)(bn_a + i);
                    const float4 b4 = *(const float4*)(bn_b + i);
                    v.x = fmaxf(fmaf(v.x, a4.x, b4.x), 0.f);
                    v.y = fmaxf(fmaf(v.y, a4.y, b4.y), 0.f);
                    v.z = fmaxf(fmaf(v.z, a4.z, b4.z), 0.f);
                    v.w = fmaxf(fmaf(v.w, a4.w, b4.w), 0.f);
                }
            }
            *(float4*)(xs + (size_t)r * LDK + kil) = v;
        }
        __syncthreads();

        // ---- compute chunk
        const float* wc = w + (size_t)kc * KCH * FOUT;
        #pragma unroll 2
        for (int k4 = 0; k4 < KCH / 4; ++k4) {
            const int ki = k4 * 4;
            float4 xv[RPG];
            #pragma unroll
            for (int r = 0; r < RPG; ++r)
                xv[r] = *(const float4*)(xs + (size_t)(r0 + r) * LDK + ki);
            #pragma unroll
            for (int j = 0; j < 4; ++j) {
                float wv[TO];
                {
                    const float4 wa = *(const float4*)(wc + (size_t)(ki + j) * FOUT + o0);
                    wv[0] = wa.x; wv[1] = wa.y; wv[2] = wa.z; wv[3] = wa.w;
                    if constexpr (TO == 8) {
                        const float4 wb = *(const float4*)(wc + (size_t)(ki + j) * FOUT + o0 + 4);
                        wv[4] = wb.x; wv[5] = wb.y; wv[6] = wb.z; wv[7] = wb.w;
                    }
                }
                #pragma unroll
                for (int r = 0; r < RPG; ++r) {
                    const float xx = (j == 0) ? xv[r].x : (j == 1) ? xv[r].y
                                   : (j == 2) ? xv[r].z : xv[r].w;
                    #pragma unroll
                    for (int t = 0; t < TO; ++t) acc[r][t] = fmaf(xx, wv[t], acc[r][t]);
                }
            }
        }
    }
    __syncthreads();   // xs dead; smem reusable for stats reduce

    float bv[TO];
    if constexpr (HAS_BIAS) {
        const float4 ba = *(const float4*)(bias + o0);
        bv[0] = ba.x; bv[1] = ba.y; bv[2] = ba.z; bv[3] = ba.w;
        if constexpr (TO == 8) {
            const float4 bb = *(const float4*)(bias + o0 + 4);
            bv[4] = bb.x; bv[5] = bb.y; bv[6] = bb.z; bv[7] = bb.w;
        }
    } else {
        #pragma unroll
        for (int t = 0; t < TO; ++t) bv[t] = 0.f;
    }

    float s[TO], q[TO];
    #pragma unroll
    for (int t = 0; t < TO; ++t) { s[t] = 0.f; q[t] = 0.f; }

    #pragma unroll
    for (int r = 0; r < RPG; ++r) {
        float v[TO];
        #pragma unroll
        for (int t = 0; t < TO; ++t) {
            v[t] = acc[r][t] + bv[t];
            if constexpr (STATS) { s[t] += v[t]; q[t] = fmaf(v[t], v[t], q[t]); }
        }
        const int m = m0 + r0 + r;
        if constexpr (PACKOUT) {
            // TO==4: othr>>1 selects z_j (0..2, 3 dummy), othr&1 selects col half
            const int zj = othr >> 1, half = othr & 1;
            if (zj < 3)
                *(float4*)(out + ((size_t)zj * BV + m) * 8 + half * 4) =
                    make_float4(v[0], v[1], v[2], v[3]);
        } else {
            float* dst = out + (size_t)m * FOUT + o0;
            *(float4*)dst = make_float4(v[0], v[1], v[2], v[3]);
            if constexpr (TO == 8)
                *(float4*)(dst + 4) = make_float4(v[4], v[5], v[6], v[7]);
        }
    }

    if constexpr (STATS) {
        float2* red = (float2*)smem;              // [RGRP][FOUT+1]
        #pragma unroll
        for (int t = 0; t < TO; ++t)
            red[(size_t)grp * (FOUT + 1) + o0 + t] = make_float2(s[t], q[t]);
        __syncthreads();
        for (int c = tid; c < FOUT; c += THREADS) {
            float rs = 0.f, rq = 0.f;
            #pragma unroll 4
            for (int g = 0; g < RGRP; ++g) {
                const float2 p = red[(size_t)g * (FOUT + 1) + c];
                rs += p.x; rq += p.y;
            }
            partial[(size_t)c * gridDim.x + blockIdx.x] = make_float2(rs, rq);
        }
    }
}

// ---------------- BN finalize: one block per channel, coalesced over [C][nblk]
__global__ __launch_bounds__(256)
void bn_finalize_kernel(const float2* __restrict__ partial,
                        const float* __restrict__ g, const float* __restrict__ b,
                        float* __restrict__ a_out, float* __restrict__ b_out,
                        float invN, int nblk)
{
    __shared__ float2 red[4];
    const int c = blockIdx.x;
    const float2* p = partial + (size_t)c * nblk;
    float s = 0.f, ss = 0.f;
    for (int k = threadIdx.x; k < nblk; k += 256) {
        const float2 v = p[k];
        s += v.x; ss += v.y;
    }
    #pragma unroll
    for (int off = 32; off > 0; off >>= 1) {
        s  += __shfl_down(s, off);
        ss += __shfl_down(ss, off);
    }
    if ((threadIdx.x & 63) == 0) red[threadIdx.x >> 6] = make_float2(s, ss);
    __syncthreads();
    if (threadIdx.x == 0) {
        float ts = 0.f, tq = 0.f;
        #pragma unroll
        for (int i = 0; i < 4; ++i) { ts += red[i].x; tq += red[i].y; }
        const float m = ts * invN;
        const float var = tq * invN - m * m;
        const float a = g[c] * rsqrtf(var + BN_EPS);
        a_out[c] = a;
        b_out[c] = b[c] - m * a;
    }
}

// ---------------- BN apply (float4), for C=256 tensors only
template<int C, bool RELU, bool ADD>
__global__ __launch_bounds__(256)
void bn_apply_kernel(float* __restrict__ out, const float* __restrict__ x,
                     const float* __restrict__ base,
                     const float* __restrict__ bn_a, const float* __restrict__ bn_b)
{
    int i = blockIdx.x * 256 + threadIdx.x;   // float4 index
    float4 v = ((const float4*)x)[i];
    int c0 = (i * 4) % C;
    float4 a4 = *reinterpret_cast<const float4*>(bn_a + c0);
    float4 b4 = *reinterpret_cast<const float4*>(bn_b + c0);
    float4 r;
    r.x = fmaf(v.x, a4.x, b4.x);
    r.y = fmaf(v.y, a4.y, b4.y);
    r.z = fmaf(v.z, a4.z, b4.z);
    r.w = fmaf(v.w, a4.w, b4.w);
    if (ADD) {
        float4 bvv = ((const float4*)base)[i];
        r.x += bvv.x; r.y += bvv.y; r.z += bvv.z; r.w += bvv.w;
    }
    if (RELU) {
        r.x = fmaxf(r.x, 0.f); r.y = fmaxf(r.y, 0.f);
        r.z = fmaxf(r.z, 0.f); r.w = fmaxf(r.w, 0.f);
    }
    ((float4*)out)[i] = r;
}

// ---------------- conv3 weight packer: [3][256][8] -> [256][32] (+ padded bias)
__global__ void pack_conv3_kernel(const float* __restrict__ w, const float* __restrict__ bias,
                                  float* __restrict__ wpack, float* __restrict__ bpack)
{
    int t = blockIdx.x * 256 + threadIdx.x;
    if (t < 256 * 32) {
        int ki = t / 32, c = t % 32;
        int j = c / 8, o = c % 8;
        wpack[t] = (j < 3) ? w[(size_t)j * 2048 + ki * 8 + o] : 0.f;
    }
    if (t < 32) bpack[t] = (t < 8) ? bias[t] : 0.f;
}

// ---------------- conv3 tail helpers
__global__ void combine_kernel(float* __restrict__ e, const float* __restrict__ z1,
                               const float* __restrict__ t)
{
    int i = blockIdx.x * 256 + threadIdx.x;
    e[i] = fmaf(2.f, t[i], z1[i]);
}

__global__ void final_add_kernel(float* __restrict__ out, const float* __restrict__ z0,
                                 const float* __restrict__ z2, const float* __restrict__ s)
{
    int i = blockIdx.x * 256 + threadIdx.x;
    out[i] = z0[i] - z2[i] + s[i];
}

extern "C" void kernel_launch(void* const* d_in, const int* in_sizes, int n_in,
                              void* d_out, int out_size, void* d_ws, size_t ws_size,
                              hipStream_t stream)
{
    const float* x       = (const float*)d_in[0];
    const int*   col     = (const int*)  d_in[2];
    const float* eval_   = (const float*)d_in[3];
    const float* conv1_w = (const float*)d_in[4];
    const float* conv1_b = (const float*)d_in[5];
    const float* bn1_g   = (const float*)d_in[6];
    const float* bn1_b   = (const float*)d_in[7];
    const float* conv2_w = (const float*)d_in[8];
    const float* conv2_b = (const float*)d_in[9];
    const float* bn2_g   = (const float*)d_in[10];
    const float* bn2_b   = (const float*)d_in[11];
    const float* bt_c1w  = (const float*)d_in[12];
    const float* bt_c1b  = (const float*)d_in[13];
    const float* bt_c2w  = (const float*)d_in[14];
    const float* bt_c2b  = (const float*)d_in[15];
    const float* bt_c3w  = (const float*)d_in[16];
    const float* bt_c3b  = (const float*)d_in[17];
    const float* btbn1g  = (const float*)d_in[18];
    const float* btbn1b  = (const float*)d_in[19];
    const float* btbn2g  = (const float*)d_in[20];
    const float* btbn2b  = (const float*)d_in[21];
    const float* btbn3g  = (const float*)d_in[22];
    const float* btbn3b  = (const float*)d_in[23];
    const float* conv3_w = (const float*)d_in[24];
    const float* conv3_b = (const float*)d_in[25];
    float* out = (float*)d_out;

    float* ws = (float*)d_ws;
    float* h2    = ws;                         // BV*256
    float* y3    = h2 + (size_t)BV * 256;      // BV*256 (aliased as stats partial)
    float* t64a  = y3 + (size_t)BV * 256;      // BV*64
    float* t64b  = t64a + (size_t)BV * 64;     // BV*64
    float* t64c  = t64b + (size_t)BV * 64;     // BV*64
    float* t64d  = t64c + (size_t)BV * 64;     // BV*64
    float* aarr  = t64d + (size_t)BV * 64;     // 11*256
    float* barr  = aarr + 11 * 256;            // 11*256
    float* wpack = barr + 11 * 256;            // 256*32
    float* bpack = wpack + 256 * 32;           // 32
    float2* partY = (float2*)y3;               // partial when y3 is dead
    float2* partC = (float2*)t64c;             // partial for cheb3 (y3 being written)

    const float invN = 1.f / (float)BV;
    const int NAPP = BV / 4;                   // blocks for C=256 bn_apply (BV*64 f4 / 256 thr)

    // ---------- Stage A: conv1 (8 -> 64), K=3 ----------
    spmm8_kernel<false><<<BV * 8 / 256, 256, 0, stream>>>(t64a, x, nullptr, eval_, col);
    spmm8_kernel<true ><<<BV * 8 / 256, 256, 0, stream>>>(t64b, t64a, x, eval_, col);
    gemm_lds_kernel<64, 24, 24, 8, 4, 16, 16, 4, 3, true, false, true, false>
        <<<BV / 64, 256, 0, stream>>>(x, t64a, t64b, conv1_w, conv1_b, nullptr, nullptr, t64c, partY);
    bn_finalize_kernel<<<64, 256, 0, stream>>>(partY, bn1_g, bn1_b, aarr, barr, invN, BV / 64);

    // ---------- Stage B: conv2 (64 -> 256), K=3, x0-BN fused ----------
    spmm64_kernel<false, true, false><<<BV * 16 / 256, 256, 0, stream>>>(t64a, t64c, nullptr, eval_, col, aarr, barr);
    spmm64_kernel<true, false, true ><<<BV * 16 / 256, 256, 0, stream>>>(t64b, t64a, t64c, eval_, col, aarr, barr);
    gemm_lds_kernel<256, 192, 96, 64, 4, 64, 4, 8, 3, true, true, true, false>
        <<<BV / 32, 256, 0, stream>>>(t64c, t64a, t64b, conv2_w, conv2_b, aarr, barr, h2, partY);
    bn_finalize_kernel<<<256, 256, 0, stream>>>(partY, bn2_g, bn2_b, aarr + 256, barr + 256, invN, BV / 32);
    bn_apply_kernel<256, true, false><<<NAPP, 256, 0, stream>>>(h2, h2, nullptr, aarr + 256, barr + 256);

    // ---------- Stage C: 3 bottlenecks ----------
    for (int i = 0; i < 3; ++i) {
        float* aA = aarr + (2 + i * 3) * 256; float* bA = barr + (2 + i * 3) * 256;
        float* aB = aarr + (3 + i * 3) * 256; float* bB = barr + (3 + i * 3) * 256;
        float* aC = aarr + (4 + i * 3) * 256; float* bC = barr + (4 + i * 3) * 256;

        // cheb1: K=1, 256->64, K-chunked, stats fused
        gemm_lds_kernel<64, 256, 128, 256, 4, 16, 16, 4, 1, true, false, true, false>
            <<<BV / 64, 256, 0, stream>>>(h2, nullptr, nullptr,
                                          bt_c1w + (size_t)i * 256 * 64, bt_c1b + i * 64,
                                          nullptr, nullptr, t64c, partY);
        bn_finalize_kernel<<<64, 256, 0, stream>>>(partY, btbn1g + i * 64, btbn1b + i * 64, aA, bA, invN, BV / 64);

        // cheb2: K=3, 64->64; BN1 fused into gathers and x0-staging
        spmm64_kernel<false, true, false><<<BV * 16 / 256, 256, 0, stream>>>(t64a, t64c, nullptr, eval_, col, aA, bA);
        spmm64_kernel<true, false, true ><<<BV * 16 / 256, 256, 0, stream>>>(t64b, t64a, t64c, eval_, col, aA, bA);
        gemm_lds_kernel<64, 192, 96, 64, 4, 16, 16, 4, 3, true, true, true, false>
            <<<BV / 64, 256, 0, stream>>>(t64c, t64a, t64b,
                                          bt_c2w + (size_t)i * 3 * 64 * 64, bt_c2b + i * 64,
                                          aA, bA, t64d, partY);
        bn_finalize_kernel<<<64, 256, 0, stream>>>(partY, btbn2g + i * 64, btbn2b + i * 64, aB, bB, invN, BV / 64);

        // cheb3: K=1, 64->256; BN2 fused into x0-staging; stats partial -> t64c
        gemm_lds_kernel<256, 64, 64, 64, 4, 64, 4, 8, 1, true, true, true, false>
            <<<BV / 32, 256, 0, stream>>>(t64d, nullptr, nullptr,
                                          bt_c3w + (size_t)i * 64 * 256, bt_c3b + i * 256,
                                          aB, bB, y3, partC);
        bn_finalize_kernel<<<256, 256, 0, stream>>>(partC, btbn3g + i * 256, btbn3b + i * 256, aC, bC, invN, BV / 32);
        // BN3 apply + residual add into h2
        bn_apply_kernel<256, false, true><<<NAPP, 256, 0, stream>>>(h2, y3, h2, aC, bC);
    }

    // ---------- Stage D: conv3 (256 -> 8), K=3, commuted: out = z0 - z2 + L(z1 + 2*L*z2) ----------
    float* z0 = t64a;
    float* z1 = z0 + (size_t)BV * 8;
    float* z2 = z1 + (size_t)BV * 8;
    float* tt = z2 + (size_t)BV * 8;
    float* ee = tt + (size_t)BV * 8;
    float* sb = ee + (size_t)BV * 8;

    pack_conv3_kernel<<<32, 256, 0, stream>>>(conv3_w, conv3_b, wpack, bpack);
    gemm_lds_kernel<32, 256, 128, 256, 4, 8, 32, 2, 1, false, false, true, true>
        <<<BV / 64, 256, 0, stream>>>(h2, nullptr, nullptr, wpack, bpack, nullptr, nullptr, z0, nullptr);

    spmm8_kernel<false><<<BV * 8 / 256, 256, 0, stream>>>(tt, z2, nullptr, eval_, col);
    combine_kernel<<<BV * 8 / 256, 256, 0, stream>>>(ee, z1, tt);
    spmm8_kernel<false><<<BV * 8 / 256, 256, 0, stream>>>(sb, ee, nullptr, eval_, col);
    final_add_kernel<<<BV * 8 / 256, 256, 0, stream>>>(out, z0, z2, sb);

    (void)in_sizes; (void)n_in; (void)out_size; (void)ws_size;
}

// Round 8
// 528.900 us; speedup vs baseline: 3.9542x; 1.2837x over previous
//
#include <hip/hip_runtime.h>

static constexpr int NBRS = 21;
static constexpr int Nv   = 12288;
static constexpr int BV   = 4 * Nv;            // 49152 rows
static constexpr float BN_EPS = 1e-5f;

typedef __bf16 bf16x4 __attribute__((ext_vector_type(4)));
typedef __bf16 bf16x8 __attribute__((ext_vector_type(8)));
typedef float  f32x4  __attribute__((ext_vector_type(4)));

// ---------------- SPMM (C=8, scalar)
template<bool CHEB2>
__global__ void spmm8_kernel(float* __restrict__ y, const float* __restrict__ x,
                             const float* __restrict__ x0,
                             const float* __restrict__ val, const int* __restrict__ col)
{
    int idx = blockIdx.x * 256 + threadIdx.x;
    int c = idx % 8;
    int v = (idx / 8) % Nv;
    int b = idx / (8 * Nv);
    int e0 = v * NBRS;
    float acc = 0.f;
    #pragma unroll
    for (int j = 0; j < NBRS; ++j) {
        int u = col[e0 + j];
        acc = fmaf(val[e0 + j], x[((size_t)b * Nv + u) * 8 + c], acc);
    }
    if (CHEB2) y[idx] = 2.f * acc - x0[idx];
    else       y[idx] = acc;
}

// ---------------- SPMM C=64, float4, optional fused BN+relu on gather and/or x0
template<bool CHEB2, bool BNG, bool BNX0>
__global__ __launch_bounds__(256)
void spmm64_kernel(float* __restrict__ y, const float* __restrict__ x,
                   const float* __restrict__ x0,
                   const float* __restrict__ val, const int* __restrict__ col,
                   const float* __restrict__ bn_a, const float* __restrict__ bn_b)
{
    int idx = blockIdx.x * 256 + threadIdx.x;   // over BV*16
    int q = idx % 16;
    int v = (idx / 16) % Nv;
    int b = idx / (16 * Nv);
    int e0 = v * NBRS;
    const float4* x4 = (const float4*)x;
    float4 a4, b4;
    if (BNG || (CHEB2 && BNX0)) {
        a4 = ((const float4*)bn_a)[q];
        b4 = ((const float4*)bn_b)[q];
    }
    float4 acc = {0.f, 0.f, 0.f, 0.f};
    #pragma unroll
    for (int j = 0; j < NBRS; ++j) {
        int u = col[e0 + j];
        float a = val[e0 + j];
        float4 xv = x4[(size_t)(b * Nv + u) * 16 + q];
        if (BNG) {
            xv.x = fmaxf(fmaf(xv.x, a4.x, b4.x), 0.f);
            xv.y = fmaxf(fmaf(xv.y, a4.y, b4.y), 0.f);
            xv.z = fmaxf(fmaf(xv.z, a4.z, b4.z), 0.f);
            xv.w = fmaxf(fmaf(xv.w, a4.w, b4.w), 0.f);
        }
        acc.x = fmaf(a, xv.x, acc.x);
        acc.y = fmaf(a, xv.y, acc.y);
        acc.z = fmaf(a, xv.z, acc.z);
        acc.w = fmaf(a, xv.w, acc.w);
    }
    if (CHEB2) {
        float4 pv = ((const float4*)x0)[idx];
        if (BNX0) {
            pv.x = fmaxf(fmaf(pv.x, a4.x, b4.x), 0.f);
            pv.y = fmaxf(fmaf(pv.y, a4.y, b4.y), 0.f);
            pv.z = fmaxf(fmaf(pv.z, a4.z, b4.z), 0.f);
            pv.w = fmaxf(fmaf(pv.w, a4.w, b4.w), 0.f);
        }
        acc.x = 2.f * acc.x - pv.x;
        acc.y = 2.f * acc.y - pv.y;
        acc.z = 2.f * acc.z - pv.z;
        acc.w = 2.f * acc.w - pv.w;
    }
    ((float4*)y)[idx] = acc;
}

// ---------------- weight pack: fp32 [K][FOUT] -> fragment-ordered bf16
// wp[((ks*NT + nt)*64 + lane)*8 + j] = w[ks*32 + (lane>>4)*8 + j][nt*16 + (lane&15)]
__global__ void pack_wb_kernel(const float* __restrict__ w, __bf16* __restrict__ wp,
                               int KSRC, int FOUT, int KPAD)
{
    int t = blockIdx.x * 256 + threadIdx.x;
    if (t >= KPAD * FOUT) return;
    int j    = t & 7;
    int lane = (t >> 3) & 63;
    int rest = t >> 9;
    int NT = FOUT >> 4;
    int nt = rest % NT;
    int ks = rest / NT;
    int k = ks * 32 + (lane >> 4) * 8 + j;
    int o = nt * 16 + (lane & 15);
    wp[t] = (k < KSRC) ? (__bf16)w[(size_t)k * FOUT + o] : (__bf16)0.f;
}

// ---------------- MFMA GEMM: out[m,o] = sum_k x[m,k] w[k,o] (+bias)
// Block: 256 thr = 4 waves; 64 rows/block (wave w -> rows w*16..w*16+15).
// x staged to LDS as bf16 (optional fused BN+relu on x0 part); w from packed bf16.
// Fused BN-stats (partial: [FOUT][grid]). PACKOUT: conv3 3x8 packed output.
template<int FOUT, int KFIN, int KPAD, int FIN, int NSRC,
         bool STATS, bool BN0, bool HAS_BIAS, bool PACKOUT>
__global__ __launch_bounds__(256)
void gemm_mfma_kernel(const float* __restrict__ x0, const float* __restrict__ x1,
                      const float* __restrict__ x2,
                      const __bf16* __restrict__ wp, const float* __restrict__ bias,
                      const float* __restrict__ bn_a, const float* __restrict__ bn_b,
                      float* __restrict__ out, float2* __restrict__ partial)
{
    constexpr int NT    = FOUT / 16;
    constexpr int NSTEP = KPAD / 32;
    constexpr int LDKB  = KPAD + 8;            // bf16 elems; row stride 16B-aligned
    constexpr size_t XS_B  = (size_t)64 * LDKB * 2;
    constexpr size_t RED_B = STATS ? (size_t)4 * FOUT * 8 : 0;
    constexpr size_t SMEM  = XS_B > RED_B ? XS_B : RED_B;
    __shared__ __align__(16) char smem[SMEM];
    __bf16* xs = (__bf16*)smem;

    const int tid = threadIdx.x;
    const int m0 = blockIdx.x * 64;

    // ---- stage x tile as bf16 (coalesced float4 reads, optional BN+relu on x0)
    constexpr int NF4 = 64 * (KPAD / 4);
    for (int f = tid; f < NF4; f += 256) {
        const int r  = f / (KPAD / 4);
        const int ki = (f % (KPAD / 4)) * 4;
        bf16x4 h;
        if (KFIN == KPAD || ki < KFIN) {
            const float* src; int i; int kk;
            if constexpr (NSRC == 1) { src = x0; i = ki; kk = 0; }
            else { kk = ki / FIN; i = ki % FIN; src = (kk == 0) ? x0 : (kk == 1 ? x1 : x2); }
            float4 v = *(const float4*)(src + (size_t)(m0 + r) * FIN + i);
            if constexpr (BN0) {
                if (NSRC == 1 || kk == 0) {
                    const float4 a4 = *(const float4*)(bn_a + i);
                    const float4 b4 = *(const float4*)(bn_b + i);
                    v.x = fmaxf(fmaf(v.x, a4.x, b4.x), 0.f);
                    v.y = fmaxf(fmaf(v.y, a4.y, b4.y), 0.f);
                    v.z = fmaxf(fmaf(v.z, a4.z, b4.z), 0.f);
                    v.w = fmaxf(fmaf(v.w, a4.w, b4.w), 0.f);
                }
            }
            h[0] = (__bf16)v.x; h[1] = (__bf16)v.y; h[2] = (__bf16)v.z; h[3] = (__bf16)v.w;
        } else {
            h[0] = (__bf16)0.f; h[1] = (__bf16)0.f; h[2] = (__bf16)0.f; h[3] = (__bf16)0.f;
        }
        *(bf16x4*)(xs + (size_t)r * LDKB + ki) = h;
    }
    __syncthreads();

    const int lane = tid & 63;
    const int wv   = tid >> 6;
    const int lo   = lane & 15;
    const int hi   = lane >> 4;

    f32x4 acc[NT];
    #pragma unroll
    for (int nt = 0; nt < NT; ++nt) acc[nt] = (f32x4){0.f, 0.f, 0.f, 0.f};

    const int arow = wv * 16 + lo;
    #pragma unroll
    for (int ks = 0; ks < NSTEP; ++ks) {
        const bf16x8 a = *(const bf16x8*)(xs + (size_t)arow * LDKB + ks * 32 + hi * 8);
        #pragma unroll
        for (int nt = 0; nt < NT; ++nt) {
            const bf16x8 b = *(const bf16x8*)(wp + ((size_t)(ks * NT + nt) * 64 + lane) * 8);
            acc[nt] = __builtin_amdgcn_mfma_f32_16x16x32_bf16(a, b, acc[nt], 0, 0, 0);
        }
    }
    __syncthreads();   // xs dead; smem reusable for stats reduce

    float2* red = (float2*)smem;   // [4][FOUT]

    #pragma unroll
    for (int nt = 0; nt < NT; ++nt) {
        const int o = nt * 16 + lo;
        const float bo = HAS_BIAS ? bias[o] : 0.f;
        float s = 0.f, q = 0.f;
        #pragma unroll
        for (int j = 0; j < 4; ++j) {
            const float v = acc[nt][j] + bo;
            const int m = m0 + wv * 16 + hi * 4 + j;
            if constexpr (PACKOUT) {
                const int zj = o >> 3;
                if (zj < 3) out[((size_t)zj * BV + m) * 8 + (o & 7)] = v;
            } else {
                out[(size_t)m * FOUT + o] = v;
            }
            if constexpr (STATS) { s += v; q = fmaf(v, v, q); }
        }
        if constexpr (STATS) {
            s += __shfl_xor(s, 16); q += __shfl_xor(q, 16);
            s += __shfl_xor(s, 32); q += __shfl_xor(q, 32);
            if (lane < 16) red[wv * FOUT + o] = make_float2(s, q);
        }
    }

    if constexpr (STATS) {
        __syncthreads();
        for (int c = tid; c < FOUT; c += 256) {
            float rs = 0.f, rq = 0.f;
            #pragma unroll
            for (int g = 0; g < 4; ++g) {
                const float2 p = red[g * FOUT + c];
                rs += p.x; rq += p.y;
            }
            partial[(size_t)c * gridDim.x + blockIdx.x] = make_float2(rs, rq);
        }
    }
}

// ---------------- BN finalize: one block per channel, coalesced over [C][nblk]
__global__ __launch_bounds__(256)
void bn_finalize_kernel(const float2* __restrict__ partial,
                        const float* __restrict__ g, const float* __restrict__ b,
                        float* __restrict__ a_out, float* __restrict__ b_out,
                        float invN, int nblk)
{
    __shared__ float2 red[4];
    const int c = blockIdx.x;
    const float2* p = partial + (size_t)c * nblk;
    float s = 0.f, ss = 0.f;
    for (int k = threadIdx.x; k < nblk; k += 256) {
        const float2 v = p[k];
        s += v.x; ss += v.y;
    }
    #pragma unroll
    for (int off = 32; off > 0; off >>= 1) {
        s  += __shfl_down(s, off);
        ss += __shfl_down(ss, off);
    }
    if ((threadIdx.x & 63) == 0) red[threadIdx.x >> 6] = make_float2(s, ss);
    __syncthreads();
    if (threadIdx.x == 0) {
        float ts = 0.f, tq = 0.f;
        #pragma unroll
        for (int i = 0; i < 4; ++i) { ts += red[i].x; tq += red[i].y; }
        const float m = ts * invN;
        const float var = tq * invN - m * m;
        const float a = g[c] * rsqrtf(var + BN_EPS);
        a_out[c] = a;
        b_out[c] = b[c] - m * a;
    }
}

// ---------------- BN apply (float4), for C=256 tensors only
template<int C, bool RELU, bool ADD>
__global__ __launch_bounds__(256)
void bn_apply_kernel(float* __restrict__ out, const float* __restrict__ x,
                     const float* __restrict__ base,
                     const float* __restrict__ bn_a, const float* __restrict__ bn_b)
{
    int i = blockIdx.x * 256 + threadIdx.x;   // float4 index
    float4 v = ((const float4*)x)[i];
    int c0 = (i * 4) % C;
    float4 a4 = *reinterpret_cast<const float4*>(bn_a + c0);
    float4 b4 = *reinterpret_cast<const float4*>(bn_b + c0);
    float4 r;
    r.x = fmaf(v.x, a4.x, b4.x);
    r.y = fmaf(v.y, a4.y, b4.y);
    r.z = fmaf(v.z, a4.z, b4.z);
    r.w = fmaf(v.w, a4.w, b4.w);
    if (ADD) {
        float4 bvv = ((const float4*)base)[i];
        r.x += bvv.x; r.y += bvv.y; r.z += bvv.z; r.w += bvv.w;
    }
    if (RELU) {
        r.x = fmaxf(r.x, 0.f); r.y = fmaxf(r.y, 0.f);
        r.z = fmaxf(r.z, 0.f); r.w = fmaxf(r.w, 0.f);
    }
    ((float4*)out)[i] = r;
}

// ---------------- conv3 weight packer: [3][256][8] -> [256][32] (+ padded bias)
__global__ void pack_conv3_kernel(const float* __restrict__ w, const float* __restrict__ bias,
                                  float* __restrict__ wpack, float* __restrict__ bpack)
{
    int t = blockIdx.x * 256 + threadIdx.x;
    if (t < 256 * 32) {
        int ki = t / 32, c = t % 32;
        int j = c / 8, o = c % 8;
        wpack[t] = (j < 3) ? w[(size_t)j * 2048 + ki * 8 + o] : 0.f;
    }
    if (t < 32) bpack[t] = (t < 8) ? bias[t] : 0.f;
}

// ---------------- conv3 tail helpers
__global__ void combine_kernel(float* __restrict__ e, const float* __restrict__ z1,
                               const float* __restrict__ t)
{
    int i = blockIdx.x * 256 + threadIdx.x;
    e[i] = fmaf(2.f, t[i], z1[i]);
}

__global__ void final_add_kernel(float* __restrict__ out, const float* __restrict__ z0,
                                 const float* __restrict__ z2, const float* __restrict__ s)
{
    int i = blockIdx.x * 256 + threadIdx.x;
    out[i] = z0[i] - z2[i] + s[i];
}

extern "C" void kernel_launch(void* const* d_in, const int* in_sizes, int n_in,
                              void* d_out, int out_size, void* d_ws, size_t ws_size,
                              hipStream_t stream)
{
    const float* x       = (const float*)d_in[0];
    const int*   col     = (const int*)  d_in[2];
    const float* eval_   = (const float*)d_in[3];
    const float* conv1_w = (const float*)d_in[4];
    const float* conv1_b = (const float*)d_in[5];
    const float* bn1_g   = (const float*)d_in[6];
    const float* bn1_b   = (const float*)d_in[7];
    const float* conv2_w = (const float*)d_in[8];
    const float* conv2_b = (const float*)d_in[9];
    const float* bn2_g   = (const float*)d_in[10];
    const float* bn2_b   = (const float*)d_in[11];
    const float* bt_c1w  = (const float*)d_in[12];
    const float* bt_c1b  = (const float*)d_in[13];
    const float* bt_c2w  = (const float*)d_in[14];
    const float* bt_c2b  = (const float*)d_in[15];
    const float* bt_c3w  = (const float*)d_in[16];
    const float* bt_c3b  = (const float*)d_in[17];
    const float* btbn1g  = (const float*)d_in[18];
    const float* btbn1b  = (const float*)d_in[19];
    const float* btbn2g  = (const float*)d_in[20];
    const float* btbn2b  = (const float*)d_in[21];
    const float* btbn3g  = (const float*)d_in[22];
    const float* btbn3b  = (const float*)d_in[23];
    const float* conv3_w = (const float*)d_in[24];
    const float* conv3_b = (const float*)d_in[25];
    float* out = (float*)d_out;

    float* ws = (float*)d_ws;
    float* h2    = ws;                         // BV*256
    float* y3    = h2 + (size_t)BV * 256;      // BV*256 (aliased as stats partial)
    float* t64a  = y3 + (size_t)BV * 256;      // BV*64
    float* t64b  = t64a + (size_t)BV * 64;     // BV*64
    float* t64c  = t64b + (size_t)BV * 64;     // BV*64
    float* t64d  = t64c + (size_t)BV * 64;     // BV*64
    float* aarr  = t64d + (size_t)BV * 64;     // 11*256
    float* barr  = aarr + 11 * 256;            // 11*256
    float* wpack = barr + 11 * 256;            // 256*32 fp32 (conv3 packed)
    float* bpack = wpack + 256 * 32;           // 32
    __bf16* wb   = (__bf16*)(bpack + 32);      // bf16 weight arena (16B aligned)
    __bf16* wp1  = wb;                         // 32*64    = 2048
    __bf16* wp2  = wp1 + 2048;                 // 192*256  = 49152
    __bf16* wpc1 = wp2 + 49152;                // 3*256*64 = 49152
    __bf16* wpc2 = wpc1 + 49152;               // 3*192*64 = 36864
    __bf16* wpc3 = wpc2 + 36864;               // 3*64*256 = 49152
    __bf16* wp3  = wpc3 + 49152;               // 256*32   = 8192
    float2* partY = (float2*)y3;               // partial when y3 is dead
    float2* partC = (float2*)t64c;             // partial for cheb3 (y3 being written)

    const float invN = 1.f / (float)BV;
    const int NGB  = BV / 64;                  // 768 MFMA GEMM blocks
    const int NAPP = BV / 4;                   // C=256 bn_apply blocks

    // ---------- weight packing (deterministic, every launch) ----------
    pack_conv3_kernel<<<32, 256, 0, stream>>>(conv3_w, conv3_b, wpack, bpack);
    pack_wb_kernel<<<8,   256, 0, stream>>>(conv1_w, wp1, 24, 64, 32);
    pack_wb_kernel<<<192, 256, 0, stream>>>(conv2_w, wp2, 192, 256, 192);
    for (int i = 0; i < 3; ++i) {
        pack_wb_kernel<<<64, 256, 0, stream>>>(bt_c1w + (size_t)i * 16384, wpc1 + (size_t)i * 16384, 256, 64, 256);
        pack_wb_kernel<<<48, 256, 0, stream>>>(bt_c2w + (size_t)i * 12288, wpc2 + (size_t)i * 12288, 192, 64, 192);
        pack_wb_kernel<<<64, 256, 0, stream>>>(bt_c3w + (size_t)i * 16384, wpc3 + (size_t)i * 16384, 64, 256, 64);
    }
    pack_wb_kernel<<<32, 256, 0, stream>>>(wpack, wp3, 256, 32, 256);

    // ---------- Stage A: conv1 (8 -> 64), K=3 ----------
    spmm8_kernel<false><<<BV * 8 / 256, 256, 0, stream>>>(t64a, x, nullptr, eval_, col);
    spmm8_kernel<true ><<<BV * 8 / 256, 256, 0, stream>>>(t64b, t64a, x, eval_, col);
    gemm_mfma_kernel<64, 24, 32, 8, 3, true, false, true, false>
        <<<NGB, 256, 0, stream>>>(x, t64a, t64b, wp1, conv1_b, nullptr, nullptr, t64c, partY);
    bn_finalize_kernel<<<64, 256, 0, stream>>>(partY, bn1_g, bn1_b, aarr, barr, invN, NGB);

    // ---------- Stage B: conv2 (64 -> 256), K=3, x0-BN fused ----------
    spmm64_kernel<false, true, false><<<BV * 16 / 256, 256, 0, stream>>>(t64a, t64c, nullptr, eval_, col, aarr, barr);
    spmm64_kernel<true, false, true ><<<BV * 16 / 256, 256, 0, stream>>>(t64b, t64a, t64c, eval_, col, aarr, barr);
    gemm_mfma_kernel<256, 192, 192, 64, 3, true, true, true, false>
        <<<NGB, 256, 0, stream>>>(t64c, t64a, t64b, wp2, conv2_b, aarr, barr, h2, partY);
    bn_finalize_kernel<<<256, 256, 0, stream>>>(partY, bn2_g, bn2_b, aarr + 256, barr + 256, invN, NGB);
    bn_apply_kernel<256, true, false><<<NAPP, 256, 0, stream>>>(h2, h2, nullptr, aarr + 256, barr + 256);

    // ---------- Stage C: 3 bottlenecks ----------
    for (int i = 0; i < 3; ++i) {
        float* aA = aarr + (2 + i * 3) * 256; float* bA = barr + (2 + i * 3) * 256;
        float* aB = aarr + (3 + i * 3) * 256; float* bB = barr + (3 + i * 3) * 256;
        float* aC = aarr + (4 + i * 3) * 256; float* bC = barr + (4 + i * 3) * 256;

        // cheb1: K=1, 256->64, stats fused
        gemm_mfma_kernel<64, 256, 256, 256, 1, true, false, true, false>
            <<<NGB, 256, 0, stream>>>(h2, nullptr, nullptr, wpc1 + (size_t)i * 16384,
                                      bt_c1b + i * 64, nullptr, nullptr, t64c, partY);
        bn_finalize_kernel<<<64, 256, 0, stream>>>(partY, btbn1g + i * 64, btbn1b + i * 64, aA, bA, invN, NGB);

        // cheb2: K=3, 64->64; BN1 fused into gathers and x0-staging
        spmm64_kernel<false, true, false><<<BV * 16 / 256, 256, 0, stream>>>(t64a, t64c, nullptr, eval_, col, aA, bA);
        spmm64_kernel<true, false, true ><<<BV * 16 / 256, 256, 0, stream>>>(t64b, t64a, t64c, eval_, col, aA, bA);
        gemm_mfma_kernel<64, 192, 192, 64, 3, true, true, true, false>
            <<<NGB, 256, 0, stream>>>(t64c, t64a, t64b, wpc2 + (size_t)i * 12288,
                                      bt_c2b + i * 64, aA, bA, t64d, partY);
        bn_finalize_kernel<<<64, 256, 0, stream>>>(partY, btbn2g + i * 64, btbn2b + i * 64, aB, bB, invN, NGB);

        // cheb3: K=1, 64->256; BN2 fused into x0-staging; stats partial -> t64c
        gemm_mfma_kernel<256, 64, 64, 64, 1, true, true, true, false>
            <<<NGB, 256, 0, stream>>>(t64d, nullptr, nullptr, wpc3 + (size_t)i * 16384,
                                      bt_c3b + i * 256, aB, bB, y3, partC);
        bn_finalize_kernel<<<256, 256, 0, stream>>>(partC, btbn3g + i * 256, btbn3b + i * 256, aC, bC, invN, NGB);
        // BN3 apply + residual add into h2
        bn_apply_kernel<256, false, true><<<NAPP, 256, 0, stream>>>(h2, y3, h2, aC, bC);
    }

    // ---------- Stage D: conv3 (256 -> 8), K=3, commuted: out = z0 - z2 + L(z1 + 2*L*z2) ----------
    float* z0 = t64a;
    float* z1 = z0 + (size_t)BV * 8;
    float* z2 = z1 + (size_t)BV * 8;
    float* tt = z2 + (size_t)BV * 8;
    float* ee = tt + (size_t)BV * 8;
    float* sb = ee + (size_t)BV * 8;

    gemm_mfma_kernel<32, 256, 256, 256, 1, false, false, true, true>
        <<<NGB, 256, 0, stream>>>(h2, nullptr, nullptr, wp3, bpack, nullptr, nullptr, z0, nullptr);

    spmm8_kernel<false><<<BV * 8 / 256, 256, 0, stream>>>(tt, z2, nullptr, eval_, col);
    combine_kernel<<<BV * 8 / 256, 256, 0, stream>>>(ee, z1, tt);
    spmm8_kernel<false><<<BV * 8 / 256, 256, 0, stream>>>(sb, ee, nullptr, eval_, col);
    final_add_kernel<<<BV * 8 / 256, 256, 0, stream>>>(out, z0, z2, sb);

    (void)in_sizes; (void)n_in; (void)out_size; (void)ws_size;
}

// Round 9
// 489.687 us; speedup vs baseline: 4.2708x; 1.0801x over previous
//
#include <hip/hip_runtime.h>

static constexpr int NBRS = 21;
static constexpr int Nv   = 12288;
static constexpr int BV   = 4 * Nv;            // 49152 rows
static constexpr float BN_EPS = 1e-5f;

typedef __bf16 bf16x4 __attribute__((ext_vector_type(4)));
typedef __bf16 bf16x8 __attribute__((ext_vector_type(8)));
typedef float  f32x4  __attribute__((ext_vector_type(4)));

// ---------------- SPMM (C=8, scalar)
template<bool CHEB2>
__global__ void spmm8_kernel(float* __restrict__ y, const float* __restrict__ x,
                             const float* __restrict__ x0,
                             const float* __restrict__ val, const int* __restrict__ col)
{
    int idx = blockIdx.x * 256 + threadIdx.x;
    int c = idx % 8;
    int v = (idx / 8) % Nv;
    int b = idx / (8 * Nv);
    int e0 = v * NBRS;
    float acc = 0.f;
    #pragma unroll
    for (int j = 0; j < NBRS; ++j) {
        int u = col[e0 + j];
        acc = fmaf(val[e0 + j], x[((size_t)b * Nv + u) * 8 + c], acc);
    }
    if (CHEB2) y[idx] = 2.f * acc - x0[idx];
    else       y[idx] = acc;
}

// ---------------- SPMM C=64, float4, optional fused BN+relu on gather and/or x0
template<bool CHEB2, bool BNG, bool BNX0>
__global__ __launch_bounds__(256)
void spmm64_kernel(float* __restrict__ y, const float* __restrict__ x,
                   const float* __restrict__ x0,
                   const float* __restrict__ val, const int* __restrict__ col,
                   const float* __restrict__ bn_a, const float* __restrict__ bn_b)
{
    int idx = blockIdx.x * 256 + threadIdx.x;   // over BV*16
    int q = idx % 16;
    int v = (idx / 16) % Nv;
    int b = idx / (16 * Nv);
    int e0 = v * NBRS;
    const float4* x4 = (const float4*)x;
    float4 a4, b4;
    if (BNG || (CHEB2 && BNX0)) {
        a4 = ((const float4*)bn_a)[q];
        b4 = ((const float4*)bn_b)[q];
    }
    float4 acc = {0.f, 0.f, 0.f, 0.f};
    #pragma unroll
    for (int j = 0; j < NBRS; ++j) {
        int u = col[e0 + j];
        float a = val[e0 + j];
        float4 xv = x4[(size_t)(b * Nv + u) * 16 + q];
        if (BNG) {
            xv.x = fmaxf(fmaf(xv.x, a4.x, b4.x), 0.f);
            xv.y = fmaxf(fmaf(xv.y, a4.y, b4.y), 0.f);
            xv.z = fmaxf(fmaf(xv.z, a4.z, b4.z), 0.f);
            xv.w = fmaxf(fmaf(xv.w, a4.w, b4.w), 0.f);
        }
        acc.x = fmaf(a, xv.x, acc.x);
        acc.y = fmaf(a, xv.y, acc.y);
        acc.z = fmaf(a, xv.z, acc.z);
        acc.w = fmaf(a, xv.w, acc.w);
    }
    if (CHEB2) {
        float4 pv = ((const float4*)x0)[idx];
        if (BNX0) {
            pv.x = fmaxf(fmaf(pv.x, a4.x, b4.x), 0.f);
            pv.y = fmaxf(fmaf(pv.y, a4.y, b4.y), 0.f);
            pv.z = fmaxf(fmaf(pv.z, a4.z, b4.z), 0.f);
            pv.w = fmaxf(fmaf(pv.w, a4.w, b4.w), 0.f);
        }
        acc.x = 2.f * acc.x - pv.x;
        acc.y = 2.f * acc.y - pv.y;
        acc.z = 2.f * acc.z - pv.z;
        acc.w = 2.f * acc.w - pv.w;
    }
    ((float4*)y)[idx] = acc;
}

// ---------------- weight pack: fp32 [K][FOUT] -> fragment-ordered bf16
__global__ void pack_wb_kernel(const float* __restrict__ w, __bf16* __restrict__ wp,
                               int KSRC, int FOUT, int KPAD)
{
    int t = blockIdx.x * 256 + threadIdx.x;
    if (t >= KPAD * FOUT) return;
    int j    = t & 7;
    int lane = (t >> 3) & 63;
    int rest = t >> 9;
    int NT = FOUT >> 4;
    int nt = rest % NT;
    int ks = rest / NT;
    int k = ks * 32 + (lane >> 4) * 8 + j;
    int o = nt * 16 + (lane & 15);
    wp[t] = (k < KSRC) ? (__bf16)w[(size_t)k * FOUT + o] : (__bf16)0.f;
}

// ---------------- MFMA GEMM: out[m,o] = sum_k x[m,k] w[k,o] (+bias)
// 256 thr = 4 waves, 64 rows/block. COLS (NT%4==0): wave w owns cols
// [w*FOUT/4 ..), all 64 rows -> B-traffic /4, LDS-repacked float4 C-write,
// shfl-only stats. Fallback row-split path for conv3 (NT=2, PACKOUT).
template<int FOUT, int KFIN, int KPAD, int FIN, int NSRC,
         bool STATS, bool BN0, bool HAS_BIAS, bool PACKOUT>
__global__ __launch_bounds__(256)
void gemm_mfma_kernel(const float* __restrict__ x0, const float* __restrict__ x1,
                      const float* __restrict__ x2,
                      const __bf16* __restrict__ wp, const float* __restrict__ bias,
                      const float* __restrict__ bn_a, const float* __restrict__ bn_b,
                      float* __restrict__ out, float2* __restrict__ partial)
{
    constexpr int NT    = FOUT / 16;
    constexpr int NSTEP = KPAD / 32;
    constexpr bool COLS = (NT % 4 == 0);
    constexpr int NT2   = COLS ? NT / 4 : NT;
    constexpr int LDKB  = KPAD + 8;            // bf16 elems; rows 16B-aligned
    constexpr int LDC   = FOUT + 4;            // repack stride (fp32)
    constexpr size_t XS_B  = (size_t)64 * LDKB * 2;
    constexpr size_t RPK_B = COLS ? (size_t)16 * LDC * 4 : 0;
    constexpr size_t SMEM  = XS_B > RPK_B ? XS_B : RPK_B;
    __shared__ __align__(16) char smem[SMEM];
    __bf16* xs = (__bf16*)smem;

    const int tid = threadIdx.x;
    const int m0 = blockIdx.x * 64;

    // ---- stage x tile as bf16 (coalesced float4 reads, optional BN+relu on x0)
    constexpr int NF4 = 64 * (KPAD / 4);
    for (int f = tid; f < NF4; f += 256) {
        const int r  = f / (KPAD / 4);
        const int ki = (f % (KPAD / 4)) * 4;
        bf16x4 h;
        if (KFIN == KPAD || ki < KFIN) {
            const float* src; int i; int kk;
            if constexpr (NSRC == 1) { src = x0; i = ki; kk = 0; }
            else { kk = ki / FIN; i = ki % FIN; src = (kk == 0) ? x0 : (kk == 1 ? x1 : x2); }
            float4 v = *(const float4*)(src + (size_t)(m0 + r) * FIN + i);
            if constexpr (BN0) {
                if (NSRC == 1 || kk == 0) {
                    const float4 a4 = *(const float4*)(bn_a + i);
                    const float4 b4 = *(const float4*)(bn_b + i);
                    v.x = fmaxf(fmaf(v.x, a4.x, b4.x), 0.f);
                    v.y = fmaxf(fmaf(v.y, a4.y, b4.y), 0.f);
                    v.z = fmaxf(fmaf(v.z, a4.z, b4.z), 0.f);
                    v.w = fmaxf(fmaf(v.w, a4.w, b4.w), 0.f);
                }
            }
            h[0] = (__bf16)v.x; h[1] = (__bf16)v.y; h[2] = (__bf16)v.z; h[3] = (__bf16)v.w;
        } else {
            h[0] = (__bf16)0.f; h[1] = (__bf16)0.f; h[2] = (__bf16)0.f; h[3] = (__bf16)0.f;
        }
        *(bf16x4*)(xs + (size_t)r * LDKB + ki) = h;
    }
    __syncthreads();

    const int lane = tid & 63;
    const int wv   = tid >> 6;
    const int lo   = lane & 15;
    const int hi   = lane >> 4;

    if constexpr (COLS) {
        f32x4 acc[4][NT2];
        #pragma unroll
        for (int mr = 0; mr < 4; ++mr)
            #pragma unroll
            for (int n = 0; n < NT2; ++n) acc[mr][n] = (f32x4){0.f, 0.f, 0.f, 0.f};

        #pragma unroll
        for (int ks = 0; ks < NSTEP; ++ks) {
            bf16x8 bfr[NT2];
            #pragma unroll
            for (int n = 0; n < NT2; ++n)
                bfr[n] = *(const bf16x8*)(wp + ((size_t)(ks * NT + wv * NT2 + n) * 64 + lane) * 8);
            bf16x8 afr[4];
            #pragma unroll
            for (int mr = 0; mr < 4; ++mr)
                afr[mr] = *(const bf16x8*)(xs + (size_t)(mr * 16 + lo) * LDKB + ks * 32 + hi * 8);
            #pragma unroll
            for (int n = 0; n < NT2; ++n)
                #pragma unroll
                for (int mr = 0; mr < 4; ++mr)
                    acc[mr][n] = __builtin_amdgcn_mfma_f32_16x16x32_bf16(afr[mr], bfr[n], acc[mr][n], 0, 0, 0);
        }

        // bias into acc
        #pragma unroll
        for (int n = 0; n < NT2; ++n) {
            const int o = wv * (FOUT / 4) + n * 16 + lo;
            const float bo = HAS_BIAS ? bias[o] : 0.f;
            #pragma unroll
            for (int mr = 0; mr < 4; ++mr)
                #pragma unroll
                for (int j = 0; j < 4; ++j) acc[mr][n][j] += bo;
        }

        // stats: column fully within wave -> shfl reduce over hi, direct write
        if constexpr (STATS) {
            #pragma unroll
            for (int n = 0; n < NT2; ++n) {
                float s = 0.f, q = 0.f;
                #pragma unroll
                for (int mr = 0; mr < 4; ++mr)
                    #pragma unroll
                    for (int j = 0; j < 4; ++j) {
                        const float v = acc[mr][n][j];
                        s += v; q = fmaf(v, v, q);
                    }
                s += __shfl_xor(s, 16); q += __shfl_xor(q, 16);
                s += __shfl_xor(s, 32); q += __shfl_xor(q, 32);
                if (lane < 16) {
                    const int o = wv * (FOUT / 4) + n * 16 + lo;
                    partial[(size_t)o * gridDim.x + blockIdx.x] = make_float2(s, q);
                }
            }
        }

        // C-write: 4 chunks of 16 rows through LDS -> cooperative float4 rows
        float* cs = (float*)smem;
        #pragma unroll
        for (int mr = 0; mr < 4; ++mr) {
            __syncthreads();
            #pragma unroll
            for (int n = 0; n < NT2; ++n) {
                const int o = wv * (FOUT / 4) + n * 16 + lo;
                #pragma unroll
                for (int j = 0; j < 4; ++j)
                    cs[(size_t)(hi * 4 + j) * LDC + o] = acc[mr][n][j];
            }
            __syncthreads();
            for (int t = tid; t < 16 * (FOUT / 4); t += 256) {
                const int rr = t / (FOUT / 4);
                const int c4 = (t % (FOUT / 4)) * 4;
                const float4 v = *(const float4*)(cs + (size_t)rr * LDC + c4);
                *(float4*)(out + (size_t)(m0 + mr * 16 + rr) * FOUT + c4) = v;
            }
        }
    } else {
        // row-split fallback (conv3: NT=2, PACKOUT, no stats)
        f32x4 acc[NT];
        #pragma unroll
        for (int nt = 0; nt < NT; ++nt) acc[nt] = (f32x4){0.f, 0.f, 0.f, 0.f};
        const int arow = wv * 16 + lo;
        #pragma unroll
        for (int ks = 0; ks < NSTEP; ++ks) {
            const bf16x8 a = *(const bf16x8*)(xs + (size_t)arow * LDKB + ks * 32 + hi * 8);
            #pragma unroll
            for (int nt = 0; nt < NT; ++nt) {
                const bf16x8 b = *(const bf16x8*)(wp + ((size_t)(ks * NT + nt) * 64 + lane) * 8);
                acc[nt] = __builtin_amdgcn_mfma_f32_16x16x32_bf16(a, b, acc[nt], 0, 0, 0);
            }
        }
        #pragma unroll
        for (int nt = 0; nt < NT; ++nt) {
            const int o = nt * 16 + lo;
            const float bo = HAS_BIAS ? bias[o] : 0.f;
            #pragma unroll
            for (int j = 0; j < 4; ++j) {
                const float v = acc[nt][j] + bo;
                const int m = m0 + wv * 16 + hi * 4 + j;
                if constexpr (PACKOUT) {
                    const int zj = o >> 3;
                    if (zj < 3) out[((size_t)zj * BV + m) * 8 + (o & 7)] = v;
                } else {
                    out[(size_t)m * FOUT + o] = v;
                }
            }
        }
    }
}

// ---------------- BN finalize: one block per channel, coalesced over [C][nblk]
__global__ __launch_bounds__(256)
void bn_finalize_kernel(const float2* __restrict__ partial,
                        const float* __restrict__ g, const float* __restrict__ b,
                        float* __restrict__ a_out, float* __restrict__ b_out,
                        float invN, int nblk)
{
    __shared__ float2 red[4];
    const int c = blockIdx.x;
    const float2* p = partial + (size_t)c * nblk;
    float s = 0.f, ss = 0.f;
    for (int k = threadIdx.x; k < nblk; k += 256) {
        const float2 v = p[k];
        s += v.x; ss += v.y;
    }
    #pragma unroll
    for (int off = 32; off > 0; off >>= 1) {
        s  += __shfl_down(s, off);
        ss += __shfl_down(ss, off);
    }
    if ((threadIdx.x & 63) == 0) red[threadIdx.x >> 6] = make_float2(s, ss);
    __syncthreads();
    if (threadIdx.x == 0) {
        float ts = 0.f, tq = 0.f;
        #pragma unroll
        for (int i = 0; i < 4; ++i) { ts += red[i].x; tq += red[i].y; }
        const float m = ts * invN;
        const float var = tq * invN - m * m;
        const float a = g[c] * rsqrtf(var + BN_EPS);
        a_out[c] = a;
        b_out[c] = b[c] - m * a;
    }
}

// ---------------- BN apply (float4), for C=256 tensors only
template<int C, bool RELU, bool ADD>
__global__ __launch_bounds__(256)
void bn_apply_kernel(float* __restrict__ out, const float* __restrict__ x,
                     const float* __restrict__ base,
                     const float* __restrict__ bn_a, const float* __restrict__ bn_b)
{
    int i = blockIdx.x * 256 + threadIdx.x;   // float4 index
    float4 v = ((const float4*)x)[i];
    int c0 = (i * 4) % C;
    float4 a4 = *reinterpret_cast<const float4*>(bn_a + c0);
    float4 b4 = *reinterpret_cast<const float4*>(bn_b + c0);
    float4 r;
    r.x = fmaf(v.x, a4.x, b4.x);
    r.y = fmaf(v.y, a4.y, b4.y);
    r.z = fmaf(v.z, a4.z, b4.z);
    r.w = fmaf(v.w, a4.w, b4.w);
    if (ADD) {
        float4 bvv = ((const float4*)base)[i];
        r.x += bvv.x; r.y += bvv.y; r.z += bvv.z; r.w += bvv.w;
    }
    if (RELU) {
        r.x = fmaxf(r.x, 0.f); r.y = fmaxf(r.y, 0.f);
        r.z = fmaxf(r.z, 0.f); r.w = fmaxf(r.w, 0.f);
    }
    ((float4*)out)[i] = r;
}

// ---------------- conv3 weight packer: [3][256][8] -> [256][32] (+ padded bias)
__global__ void pack_conv3_kernel(const float* __restrict__ w, const float* __restrict__ bias,
                                  float* __restrict__ wpack, float* __restrict__ bpack)
{
    int t = blockIdx.x * 256 + threadIdx.x;
    if (t < 256 * 32) {
        int ki = t / 32, c = t % 32;
        int j = c / 8, o = c % 8;
        wpack[t] = (j < 3) ? w[(size_t)j * 2048 + ki * 8 + o] : 0.f;
    }
    if (t < 32) bpack[t] = (t < 8) ? bias[t] : 0.f;
}

// ---------------- conv3 tail helpers
__global__ void combine_kernel(float* __restrict__ e, const float* __restrict__ z1,
                               const float* __restrict__ t)
{
    int i = blockIdx.x * 256 + threadIdx.x;
    e[i] = fmaf(2.f, t[i], z1[i]);
}

__global__ void final_add_kernel(float* __restrict__ out, const float* __restrict__ z0,
                                 const float* __restrict__ z2, const float* __restrict__ s)
{
    int i = blockIdx.x * 256 + threadIdx.x;
    out[i] = z0[i] - z2[i] + s[i];
}

extern "C" void kernel_launch(void* const* d_in, const int* in_sizes, int n_in,
                              void* d_out, int out_size, void* d_ws, size_t ws_size,
                              hipStream_t stream)
{
    const float* x       = (const float*)d_in[0];
    const int*   col     = (const int*)  d_in[2];
    const float* eval_   = (const float*)d_in[3];
    const float* conv1_w = (const float*)d_in[4];
    const float* conv1_b = (const float*)d_in[5];
    const float* bn1_g   = (const float*)d_in[6];
    const float* bn1_b   = (const float*)d_in[7];
    const float* conv2_w = (const float*)d_in[8];
    const float* conv2_b = (const float*)d_in[9];
    const float* bn2_g   = (const float*)d_in[10];
    const float* bn2_b   = (const float*)d_in[11];
    const float* bt_c1w  = (const float*)d_in[12];
    const float* bt_c1b  = (const float*)d_in[13];
    const float* bt_c2w  = (const float*)d_in[14];
    const float* bt_c2b  = (const float*)d_in[15];
    const float* bt_c3w  = (const float*)d_in[16];
    const float* bt_c3b  = (const float*)d_in[17];
    const float* btbn1g  = (const float*)d_in[18];
    const float* btbn1b  = (const float*)d_in[19];
    const float* btbn2g  = (const float*)d_in[20];
    const float* btbn2b  = (const float*)d_in[21];
    const float* btbn3g  = (const float*)d_in[22];
    const float* btbn3b  = (const float*)d_in[23];
    const float* conv3_w = (const float*)d_in[24];
    const float* conv3_b = (const float*)d_in[25];
    float* out = (float*)d_out;

    float* ws = (float*)d_ws;
    float* h2    = ws;                         // BV*256
    float* y3    = h2 + (size_t)BV * 256;      // BV*256 (aliased as stats partial)
    float* t64a  = y3 + (size_t)BV * 256;      // BV*64
    float* t64b  = t64a + (size_t)BV * 64;     // BV*64
    float* t64c  = t64b + (size_t)BV * 64;     // BV*64
    float* t64d  = t64c + (size_t)BV * 64;     // BV*64
    float* aarr  = t64d + (size_t)BV * 64;     // 11*256
    float* barr  = aarr + 11 * 256;            // 11*256
    float* wpack = barr + 11 * 256;            // 256*32 fp32 (conv3 packed)
    float* bpack = wpack + 256 * 32;           // 32
    __bf16* wb   = (__bf16*)(bpack + 32);      // bf16 weight arena (16B aligned)
    __bf16* wp1  = wb;                         // 32*64    = 2048
    __bf16* wp2  = wp1 + 2048;                 // 192*256  = 49152
    __bf16* wpc1 = wp2 + 49152;                // 3*256*64 = 49152
    __bf16* wpc2 = wpc1 + 49152;               // 3*192*64 = 36864
    __bf16* wpc3 = wpc2 + 36864;               // 3*64*256 = 49152
    __bf16* wp3  = wpc3 + 49152;               // 256*32   = 8192
    float2* partY = (float2*)y3;               // partial when y3 is dead
    float2* partC = (float2*)t64c;             // partial for cheb3 (y3 being written)

    const float invN = 1.f / (float)BV;
    const int NGB  = BV / 64;                  // 768 MFMA GEMM blocks
    const int NAPP = BV / 4;                   // C=256 bn_apply blocks

    // ---------- weight packing (deterministic, every launch) ----------
    pack_conv3_kernel<<<32, 256, 0, stream>>>(conv3_w, conv3_b, wpack, bpack);
    pack_wb_kernel<<<8,   256, 0, stream>>>(conv1_w, wp1, 24, 64, 32);
    pack_wb_kernel<<<192, 256, 0, stream>>>(conv2_w, wp2, 192, 256, 192);
    for (int i = 0; i < 3; ++i) {
        pack_wb_kernel<<<64, 256, 0, stream>>>(bt_c1w + (size_t)i * 16384, wpc1 + (size_t)i * 16384, 256, 64, 256);
        pack_wb_kernel<<<48, 256, 0, stream>>>(bt_c2w + (size_t)i * 12288, wpc2 + (size_t)i * 12288, 192, 64, 192);
        pack_wb_kernel<<<64, 256, 0, stream>>>(bt_c3w + (size_t)i * 16384, wpc3 + (size_t)i * 16384, 64, 256, 64);
    }
    pack_wb_kernel<<<32, 256, 0, stream>>>(wpack, wp3, 256, 32, 256);

    // ---------- Stage A: conv1 (8 -> 64), K=3 ----------
    spmm8_kernel<false><<<BV * 8 / 256, 256, 0, stream>>>(t64a, x, nullptr, eval_, col);
    spmm8_kernel<true ><<<BV * 8 / 256, 256, 0, stream>>>(t64b, t64a, x, eval_, col);
    gemm_mfma_kernel<64, 24, 32, 8, 3, true, false, true, false>
        <<<NGB, 256, 0, stream>>>(x, t64a, t64b, wp1, conv1_b, nullptr, nullptr, t64c, partY);
    bn_finalize_kernel<<<64, 256, 0, stream>>>(partY, bn1_g, bn1_b, aarr, barr, invN, NGB);

    // ---------- Stage B: conv2 (64 -> 256), K=3, x0-BN fused ----------
    spmm64_kernel<false, true, false><<<BV * 16 / 256, 256, 0, stream>>>(t64a, t64c, nullptr, eval_, col, aarr, barr);
    spmm64_kernel<true, false, true ><<<BV * 16 / 256, 256, 0, stream>>>(t64b, t64a, t64c, eval_, col, aarr, barr);
    gemm_mfma_kernel<256, 192, 192, 64, 3, true, true, true, false>
        <<<NGB, 256, 0, stream>>>(t64c, t64a, t64b, wp2, conv2_b, aarr, barr, h2, partY);
    bn_finalize_kernel<<<256, 256, 0, stream>>>(partY, bn2_g, bn2_b, aarr + 256, barr + 256, invN, NGB);
    bn_apply_kernel<256, true, false><<<NAPP, 256, 0, stream>>>(h2, h2, nullptr, aarr + 256, barr + 256);

    // ---------- Stage C: 3 bottlenecks ----------
    for (int i = 0; i < 3; ++i) {
        float* aA = aarr + (2 + i * 3) * 256; float* bA = barr + (2 + i * 3) * 256;
        float* aB = aarr + (3 + i * 3) * 256; float* bB = barr + (3 + i * 3) * 256;
        float* aC = aarr + (4 + i * 3) * 256; float* bC = barr + (4 + i * 3) * 256;

        // cheb1: K=1, 256->64, stats fused
        gemm_mfma_kernel<64, 256, 256, 256, 1, true, false, true, false>
            <<<NGB, 256, 0, stream>>>(h2, nullptr, nullptr, wpc1 + (size_t)i * 16384,
                                      bt_c1b + i * 64, nullptr, nullptr, t64c, partY);
        bn_finalize_kernel<<<64, 256, 0, stream>>>(partY, btbn1g + i * 64, btbn1b + i * 64, aA, bA, invN, NGB);

        // cheb2: K=3, 64->64; BN1 fused into gathers and x0-staging
        spmm64_kernel<false, true, false><<<BV * 16 / 256, 256, 0, stream>>>(t64a, t64c, nullptr, eval_, col, aA, bA);
        spmm64_kernel<true, false, true ><<<BV * 16 / 256, 256, 0, stream>>>(t64b, t64a, t64c, eval_, col, aA, bA);
        gemm_mfma_kernel<64, 192, 192, 64, 3, true, true, true, false>
            <<<NGB, 256, 0, stream>>>(t64c, t64a, t64b, wpc2 + (size_t)i * 12288,
                                      bt_c2b + i * 64, aA, bA, t64d, partY);
        bn_finalize_kernel<<<64, 256, 0, stream>>>(partY, btbn2g + i * 64, btbn2b + i * 64, aB, bB, invN, NGB);

        // cheb3: K=1, 64->256; BN2 fused into x0-staging; stats partial -> t64c
        gemm_mfma_kernel<256, 64, 64, 64, 1, true, true, true, false>
            <<<NGB, 256, 0, stream>>>(t64d, nullptr, nullptr, wpc3 + (size_t)i * 16384,
                                      bt_c3b + i * 256, aB, bB, y3, partC);
        bn_finalize_kernel<<<256, 256, 0, stream>>>(partC, btbn3g + i * 256, btbn3b + i * 256, aC, bC, invN, NGB);
        // BN3 apply + residual add into h2
        bn_apply_kernel<256, false, true><<<NAPP, 256, 0, stream>>>(h2, y3, h2, aC, bC);
    }

    // ---------- Stage D: conv3 (256 -> 8), K=3, commuted: out = z0 - z2 + L(z1 + 2*L*z2) ----------
    float* z0 = t64a;
    float* z1 = z0 + (size_t)BV * 8;
    float* z2 = z1 + (size_t)BV * 8;
    float* tt = z2 + (size_t)BV * 8;
    float* ee = tt + (size_t)BV * 8;
    float* sb = ee + (size_t)BV * 8;

    gemm_mfma_kernel<32, 256, 256, 256, 1, false, false, true, true>
        <<<NGB, 256, 0, stream>>>(h2, nullptr, nullptr, wp3, bpack, nullptr, nullptr, z0, nullptr);

    spmm8_kernel<false><<<BV * 8 / 256, 256, 0, stream>>>(tt, z2, nullptr, eval_, col);
    combine_kernel<<<BV * 8 / 256, 256, 0, stream>>>(ee, z1, tt);
    spmm8_kernel<false><<<BV * 8 / 256, 256, 0, stream>>>(sb, ee, nullptr, eval_, col);
    final_add_kernel<<<BV * 8 / 256, 256, 0, stream>>>(out, z0, z2, sb);

    (void)in_sizes; (void)n_in; (void)out_size; (void)ws_size;
}